// Round 6
// baseline (524.974 us; speedup 1.0000x reference)
//
#include <hip/hip_runtime.h>
#include <math.h>

#define DIMN 1024
#define NH 8
#define ND 64
#define LSEQ 256
#define HD 512      // NH*ND

typedef __attribute__((ext_vector_type(8))) short short8;
typedef __attribute__((ext_vector_type(4))) float f32x4;

__device__ __forceinline__ float2 cmul(float2 a, float2 b){
    return make_float2(a.x*b.x - a.y*b.y, a.x*b.y + a.y*b.x);
}
__device__ __forceinline__ ushort f2bf(float f){
    union { float f; unsigned u; } v; v.f = f;
    unsigned r = v.u + 0x7FFF + ((v.u >> 16) & 1);   // RNE
    return (ushort)(r >> 16);
}

// ---------- complex 64x64 inverse per head: register-resident in-place GJ ----------
// Lane l owns column l; wave w owns rows 16w..16w+15 -> float2 a[16] in VGPRs.
// Per step: owner wave scales pivot row (shfl for M[k][k]), writes 512B row to
// double-buffered LDS; ONE barrier; every wave shfl-broadcasts f=M[r][k] from
// lane k and does the rank-1 update in registers. In-place GJ: a[k][k]=p,
// a[i][k]=-f*p, a[k][j]*=p, a[i][j]-=f*a[k][j]  (verified on 2x2 by hand).
__global__ __launch_bounds__(256) void inv_kernel(const float* __restrict__ Vr,
                                                  const float* __restrict__ Vi,
                                                  float2* __restrict__ Vinv){
    __shared__ float2 spr_buf[2][64];
    const int h = blockIdx.x;
    const int tid = threadIdx.x;
    const int w = tid >> 6, l = tid & 63;
    const int rbase = w * 16;
    float2 a[16];
    #pragma unroll
    for (int rr = 0; rr < 16; ++rr){
        int r = rbase + rr;
        a[rr] = make_float2(Vr[h*4096 + r*64 + l], Vi[h*4096 + r*64 + l]);
    }
    for (int k = 0; k < 64; ++k){
        const int kw = k >> 4, kr = k & 15;
        if (w == kw){                                   // wave-uniform
            float2 prow = a[kr];
            float2 d; d.x = __shfl(prow.x, k); d.y = __shfl(prow.y, k);
            float im = 1.f/(d.x*d.x + d.y*d.y);
            float2 p = make_float2(d.x*im, -d.y*im);
            float2 spr = (l == k) ? p : cmul(prow, p);
            a[kr] = spr;
            spr_buf[k & 1][l] = spr;
        }
        __syncthreads();
        float2 sprl = spr_buf[k & 1][l];
        float2 p; p.x = __shfl(sprl.x, k); p.y = __shfl(sprl.y, k);
        #pragma unroll
        for (int rr = 0; rr < 16; ++rr){
            if (w == kw && rr == kr) continue;          // wave-uniform skip
            float2 f; f.x = __shfl(a[rr].x, k); f.y = __shfl(a[rr].y, k);
            float2 upd;
            if (l == k){
                upd.x = -(f.x*p.x - f.y*p.y);
                upd.y = -(f.x*p.y + f.y*p.x);
            } else {
                upd.x = a[rr].x - (f.x*sprl.x - f.y*sprl.y);
                upd.y = a[rr].y - (f.x*sprl.y + f.y*sprl.x);
            }
            a[rr] = upd;
        }
        // no second barrier: step-k readers drained at barrier k before the
        // step-(k+1) owner can overwrite the opposite-parity buffer
    }
    #pragma unroll
    for (int rr = 0; rr < 16; ++rr){
        int r = rbase + rr;
        Vinv[h*4096 + r*64 + l] = a[rr];
    }
}

// ---------- W (K x N fp32) -> Wt (N x K bf16) transpose+convert ----------
__global__ __launch_bounds__(256) void transpose_cvt(const float* __restrict__ W,
                 ushort* __restrict__ Wt, int K, int N){
    __shared__ float tile[32][33];
    const int n0 = blockIdx.x * 32, k0 = blockIdx.y * 32;
    const int tx = threadIdx.x & 31, ty = threadIdx.x >> 5;   // ty 0..7
    #pragma unroll
    for (int i = 0; i < 4; ++i)
        tile[ty + i*8][tx] = W[(k0 + ty + i*8)*N + n0 + tx];
    __syncthreads();
    #pragma unroll
    for (int i = 0; i < 4; ++i){
        int r = ty + i*8;
        Wt[(n0 + r)*K + k0 + tx] = f2bf(tile[tx][r]);
    }
}

// ---------- fp32 -> bf16 elementwise (x) ----------
__global__ __launch_bounds__(256) void cvt_bf16_kernel(const float* __restrict__ in,
                                 ushort* __restrict__ o, int n4){
    int i = blockIdx.x*256 + threadIdx.x;
    if (i < n4){
        float4 v = ((const float4*)in)[i];
        ushort4 u; u.x=f2bf(v.x); u.y=f2bf(v.y); u.z=f2bf(v.z); u.w=f2bf(v.w);
        ((ushort4*)o)[i] = u;
    }
}

// ---------- bf16 MFMA GEMM: C(MxN) = act(A(MxK) @ Bt(NxK)^T + bias) ----------
#define BM 128
#define BN 128
#define BK 32
#define ASTR 40
template<int ACT>
__global__ __launch_bounds__(256) void gemm_bt(const ushort* __restrict__ A,
                 const ushort* __restrict__ Bt, const float* __restrict__ bias,
                 float* __restrict__ Cf, ushort* __restrict__ Cb,
                 float2* __restrict__ XCo, float2* __restrict__ Ao,
                 int M, int N, int K){
    __shared__ ushort As[BM*ASTR];
    __shared__ ushort Bs[BN*ASTR];
    const int tid = threadIdx.x;
    const int bm = blockIdx.y * BM, bn = blockIdx.x * BN;
    const int wave = tid >> 6, l = tid & 63;
    const int wr = (wave >> 1) * 64, wc = (wave & 1) * 64;
    const int ml = l & 15, quad = l >> 4;
    f32x4 acc[4][4];
    #pragma unroll
    for (int i=0;i<4;++i)
        #pragma unroll
        for (int j=0;j<4;++j) acc[i][j] = (f32x4){0.f,0.f,0.f,0.f};

    const int c0r = tid >> 1;
    const int c0s = (tid & 1) * 2;
    for (int k0 = 0; k0 < K; k0 += BK){
        uint4 av0 = *(const uint4*)&A [(bm + c0r)*K + k0 + c0s*8];
        uint4 av1 = *(const uint4*)&A [(bm + c0r)*K + k0 + c0s*8 + 8];
        uint4 bv0 = *(const uint4*)&Bt[(bn + c0r)*K + k0 + c0s*8];
        uint4 bv1 = *(const uint4*)&Bt[(bn + c0r)*K + k0 + c0s*8 + 8];
        __syncthreads();
        *(uint4*)&As[c0r*ASTR + c0s*8]     = av0;
        *(uint4*)&As[c0r*ASTR + c0s*8 + 8] = av1;
        *(uint4*)&Bs[c0r*ASTR + c0s*8]     = bv0;
        *(uint4*)&Bs[c0r*ASTR + c0s*8 + 8] = bv1;
        __syncthreads();
        short8 af[4], bfv[4];
        #pragma unroll
        for (int f=0; f<4; ++f){
            af[f]  = *(const short8*)&As[(wr + f*16 + ml)*ASTR + quad*8];
            bfv[f] = *(const short8*)&Bs[(wc + f*16 + ml)*ASTR + quad*8];
        }
        #pragma unroll
        for (int i=0;i<4;++i)
            #pragma unroll
            for (int j=0;j<4;++j)
                acc[i][j] = __builtin_amdgcn_mfma_f32_16x16x32_bf16(af[i], bfv[j], acc[i][j], 0,0,0);
    }
    #pragma unroll
    for (int i=0;i<4;++i){
        #pragma unroll
        for (int j=0;j<4;++j){
            const int gcol = bn + wc + j*16 + ml;
            const float bsv = bias[gcol];
            #pragma unroll
            for (int r=0;r<4;++r){
                const int grow = bm + wr + i*16 + quad*4 + r;
                float val = acc[i][j][r] + bsv;
                if (ACT == 2){
                    float v1 = __shfl_down(val, 1);
                    float v2 = __shfl_down(val, 2);
                    float v3 = __shfl_down(val, 3);
                    if ((l & 3) == 0){
                        int hd = gcol >> 2;
                        XCo[grow*HD + hd] = make_float2(val, v1);
                        float m2 = v2*v2 + v3*v3;
                        float s = sqrtf(m2)/(1.f + m2);
                        Ao[grow*HD + hd] = make_float2(v2*s, v3*s);
                    }
                } else if (ACT == 1){
                    val *= 1.f/(1.f + expf(-val));
                    Cb[grow*N + gcol] = f2bf(val);
                } else {
                    Cf[grow*N + gcol] = val;
                }
            }
        }
    }
}

// ---------- u[c] = Vinv_h @ (c==0 ? hidden : xc[c-1]),  c = 0..256 ----------
__global__ __launch_bounds__(256) void uext_kernel(const float2* __restrict__ Vinv,
                            const float* __restrict__ hre, const float* __restrict__ him,
                            const float2* __restrict__ XC, float2* __restrict__ Uext){
    int g = blockIdx.x*256 + threadIdx.x;
    int c = g >> 9;
    int hn = g & 511;
    int h = hn >> 6;
    const float2* vrow = &Vinv[hn*64];
    float2 acc = make_float2(0.f, 0.f);
    if (c == 0){
        #pragma unroll 8
        for (int o=0;o<64;++o){
            float2 x = make_float2(hre[h*64+o], him[h*64+o]);
            float2 p = cmul(vrow[o], x);
            acc.x += p.x; acc.y += p.y;
        }
    } else {
        const float2* xrow = &XC[(c-1)*HD + h*64];
        #pragma unroll 8
        for (int o=0;o<64;++o){
            float2 p = cmul(vrow[o], xrow[o]);
            acc.x += p.x; acc.y += p.y;
        }
    }
    Uext[g] = acc;
}

// ---------- sequential complex scan ----------
__global__ __launch_bounds__(512) void scan_kernel(const float2* __restrict__ Uext,
                            const float2* __restrict__ A, float2* __restrict__ S){
    int t = threadIdx.x;
    float2 st = Uext[t];
    for (int m = 0; m < LSEQ; ++m){
        float2 a = A[m*HD + t];
        float2 u = Uext[(m+1)*HD + t];
        float2 ns;
        ns.x = a.x*st.x - a.y*st.y + u.x;
        ns.y = a.x*st.y + a.y*st.x + u.y;
        st = ns;
        S[m*HD + t] = st;
    }
}

// ---------- h[m] = V_h @ S[m]; hr as bf16; fp32 tail ----------
__global__ __launch_bounds__(256) void vmul_kernel(const float* __restrict__ Vr,
                            const float* __restrict__ Vi,
                            const float2* __restrict__ S, ushort* __restrict__ hrb,
                            float* __restrict__ out_tail, int tail_n){
    int g = blockIdx.x*256 + threadIdx.x;
    int m = g >> 9, hn = g & 511;
    int h = hn >> 6;
    const float* vr = &Vr[hn*64];
    const float* vi = &Vi[hn*64];
    const float2* srow = &S[m*HD + h*64];
    float2 acc = make_float2(0.f, 0.f);
    #pragma unroll 8
    for (int o=0;o<64;++o){
        float2 v = make_float2(vr[o], vi[o]);
        float2 p = cmul(v, srow[o]);
        acc.x += p.x; acc.y += p.y;
    }
    hrb[m*DIMN + hn*2]   = f2bf(acc.x);
    hrb[m*DIMN + hn*2+1] = f2bf(acc.y);
    if (m == LSEQ-1){
        if (tail_n >= 1024){
            out_tail[hn]       = acc.x;
            out_tail[512 + hn] = acc.y;
        } else if (tail_n >= 512){
            out_tail[hn] = acc.x;
        }
    }
}

extern "C" void kernel_launch(void* const* d_in, const int* in_sizes, int n_in,
                              void* d_out, int out_size, void* d_ws, size_t ws_size,
                              hipStream_t stream) {
    const float* x      = (const float*)d_in[0];
    const float* hidr   = (const float*)d_in[1];
    const float* hidi   = (const float*)d_in[2];
    const float* w_in1  = (const float*)d_in[3];
    const float* b_in1  = (const float*)d_in[4];
    const float* w_in2  = (const float*)d_in[5];
    const float* b_in2  = (const float*)d_in[6];
    const float* w_out1 = (const float*)d_in[7];
    const float* b_out1 = (const float*)d_in[8];
    const float* w_out2 = (const float*)d_in[9];
    const float* b_out2 = (const float*)d_in[10];
    const float* Vr     = (const float*)d_in[11];
    const float* Vi     = (const float*)d_in[12];
    float* out = (float*)d_out;

    char* ws = (char*)d_ws;
    float2* Vinv  = (float2*)(ws + 0);          // 262144
    ushort* wt    = (ushort*)(ws + 262144);     // 4 MB, reused for all 4 weights
    ushort* x_bf  = (ushort*)(ws + 4456448);    // 512 KB, later reused as y1_bf
    ushort* t1_bf = (ushort*)(ws + 4980736);    // 512 KB, later reused as hr_bf
    float2* XC    = (float2*)(ws + 5505024);    // 1 MB, later reused as S
    float2* Aseq  = (float2*)(ws + 6553600);    // 1 MB
    float2* Uext  = (float2*)(ws + 7602176);    // 1052672
    ushort* y1_bf = x_bf;
    ushort* hr_bf = t1_bf;
    float2* S     = XC;

    const int tail_n = out_size - LSEQ*DIMN;

    inv_kernel<<<NH, 256, 0, stream>>>(Vr, Vi, Vinv);

    cvt_bf16_kernel<<<LSEQ*DIMN/4/256, 256, 0, stream>>>(x, x_bf, LSEQ*DIMN/4);
    transpose_cvt<<<dim3(32,32), 256, 0, stream>>>(w_in1, wt, DIMN, DIMN);
    gemm_bt<1><<<dim3(8,2), 256, 0, stream>>>(x_bf, wt, b_in1, nullptr, t1_bf,
                                              nullptr, nullptr, LSEQ, DIMN, DIMN);
    transpose_cvt<<<dim3(64,32), 256, 0, stream>>>(w_in2, wt, DIMN, 2048);
    gemm_bt<2><<<dim3(16,2), 256, 0, stream>>>(t1_bf, wt, b_in2, nullptr, nullptr,
                                               XC, Aseq, LSEQ, 2048, DIMN);
    uext_kernel<<<(LSEQ+1)*HD/256, 256, 0, stream>>>(Vinv, hidr, hidi, XC, Uext);
    scan_kernel<<<1, 512, 0, stream>>>(Uext, Aseq, S);
    vmul_kernel<<<LSEQ*HD/256, 256, 0, stream>>>(Vr, Vi, S, hr_bf, out + LSEQ*DIMN, tail_n);
    transpose_cvt<<<dim3(32,32), 256, 0, stream>>>(w_out1, wt, DIMN, DIMN);
    gemm_bt<1><<<dim3(8,2), 256, 0, stream>>>(hr_bf, wt, b_out1, nullptr, y1_bf,
                                              nullptr, nullptr, LSEQ, DIMN, DIMN);
    transpose_cvt<<<dim3(32,32), 256, 0, stream>>>(w_out2, wt, DIMN, DIMN);
    gemm_bt<0><<<dim3(8,2), 256, 0, stream>>>(y1_bf, wt, b_out2, out, nullptr,
                                              nullptr, nullptr, LSEQ, DIMN, DIMN);
}

// Round 7
// 383.764 us; speedup vs baseline: 1.3680x; 1.3680x over previous
//
#include <hip/hip_runtime.h>
#include <math.h>

#define DIMN 1024
#define NH 8
#define ND 64
#define LSEQ 256
#define HD 512      // NH*ND

typedef __attribute__((ext_vector_type(8))) short short8;
typedef __attribute__((ext_vector_type(4))) float f32x4;

__device__ __forceinline__ float2 cmul(float2 a, float2 b){
    return make_float2(a.x*b.x - a.y*b.y, a.x*b.y + a.y*b.x);
}
__device__ __forceinline__ ushort f2bf(float f){
    union { float f; unsigned u; } v; v.f = f;
    unsigned r = v.u + 0x7FFF + ((v.u >> 16) & 1);   // RNE
    return (ushort)(r >> 16);
}

// ---------- complex 64x64 inverse per head (Gauss-Jordan, NO pivoting) ----------
// R4 LDS structure (known-good 124us) at 512 threads / 8 waves for latency
// hiding: wave w owns rows 8w..8w+7, lane l owns cols {l, l+64}. 2 barriers
// per step. Row stride 129 (odd) -> conflict-free. Register-GJ (R6) spilled
// to scratch (VGPR=28 < 32 needed) — abandoned.
#define MSTR 129
__global__ __launch_bounds__(512) void inv_kernel(const float* __restrict__ Vr,
                                                  const float* __restrict__ Vi,
                                                  float2* __restrict__ Vinv){
    __shared__ float2 Mx[64*MSTR];
    const int h = blockIdx.x;
    const int tid = threadIdx.x;
    for (int idx = tid; idx < 64*128; idx += 512){
        int i = idx >> 7, j = idx & 127;
        float2 v;
        if (j < 64) v = make_float2(Vr[h*4096 + i*64 + j], Vi[h*4096 + i*64 + j]);
        else        v = make_float2((j-64)==i ? 1.f : 0.f, 0.f);
        Mx[i*MSTR + j] = v;
    }
    __syncthreads();
    const int w = tid >> 6, l = tid & 63;
    const int rbase = w*8;
    for (int k = 0; k < 64; ++k){
        // ---- phase A: cache pivot row (scaled) + my column-k factors ----
        float2 d = Mx[k*MSTR + k];              // broadcast read
        float im = 1.f/(d.x*d.x + d.y*d.y);
        float2 dinv = make_float2(d.x*im, -d.y*im);
        float2 spr0 = cmul(Mx[k*MSTR + l],      dinv);
        float2 spr1 = cmul(Mx[k*MSTR + l + 64], dinv);
        float2 fv[8];
        #pragma unroll
        for (int rr = 0; rr < 8; ++rr)
            fv[rr] = Mx[(rbase+rr)*MSTR + k];   // broadcast (wave-uniform addr)
        __syncthreads();
        // ---- phase B: in-place update; owner-only writes ----
        #pragma unroll
        for (int rr = 0; rr < 8; ++rr){
            int r = rbase + rr;
            if (r == k){                         // wave-uniform branch
                Mx[r*MSTR + l]      = spr0;
                Mx[r*MSTR + l + 64] = spr1;
            } else {
                float2 f  = fv[rr];
                float2 v0 = Mx[r*MSTR + l];
                float2 v1 = Mx[r*MSTR + l + 64];
                v0.x -= f.x*spr0.x - f.y*spr0.y;  v0.y -= f.x*spr0.y + f.y*spr0.x;
                v1.x -= f.x*spr1.x - f.y*spr1.y;  v1.y -= f.x*spr1.y + f.y*spr1.x;
                Mx[r*MSTR + l]      = v0;
                Mx[r*MSTR + l + 64] = v1;
            }
        }
        __syncthreads();
    }
    for (int idx = tid; idx < 64*64; idx += 512){
        int i = idx >> 6, jj = idx & 63;
        Vinv[h*4096 + idx] = Mx[i*MSTR + 64 + jj];
    }
}

// ---------- W (K x N fp32) -> Wt (N x K bf16) transpose+convert ----------
__global__ __launch_bounds__(256) void transpose_cvt(const float* __restrict__ W,
                 ushort* __restrict__ Wt, int K, int N){
    __shared__ float tile[32][33];
    const int n0 = blockIdx.x * 32, k0 = blockIdx.y * 32;
    const int tx = threadIdx.x & 31, ty = threadIdx.x >> 5;   // ty 0..7
    #pragma unroll
    for (int i = 0; i < 4; ++i)
        tile[ty + i*8][tx] = W[(k0 + ty + i*8)*N + n0 + tx];
    __syncthreads();
    #pragma unroll
    for (int i = 0; i < 4; ++i){
        int r = ty + i*8;
        Wt[(n0 + r)*K + k0 + tx] = f2bf(tile[tx][r]);
    }
}

// ---------- fp32 -> bf16 elementwise (x) ----------
__global__ __launch_bounds__(256) void cvt_bf16_kernel(const float* __restrict__ in,
                                 ushort* __restrict__ o, int n4){
    int i = blockIdx.x*256 + threadIdx.x;
    if (i < n4){
        float4 v = ((const float4*)in)[i];
        ushort4 u; u.x=f2bf(v.x); u.y=f2bf(v.y); u.z=f2bf(v.z); u.w=f2bf(v.w);
        ((ushort4*)o)[i] = u;
    }
}

// ---------- bf16 MFMA GEMM: C(MxN) = act(A(MxK) @ Bt(NxK)^T + bias) ----------
#define BM 128
#define BN 128
#define BK 32
#define ASTR 40
template<int ACT>
__global__ __launch_bounds__(256) void gemm_bt(const ushort* __restrict__ A,
                 const ushort* __restrict__ Bt, const float* __restrict__ bias,
                 float* __restrict__ Cf, ushort* __restrict__ Cb,
                 float2* __restrict__ XCo, float2* __restrict__ Ao,
                 int M, int N, int K){
    __shared__ ushort As[BM*ASTR];
    __shared__ ushort Bs[BN*ASTR];
    const int tid = threadIdx.x;
    const int bm = blockIdx.y * BM, bn = blockIdx.x * BN;
    const int wave = tid >> 6, l = tid & 63;
    const int wr = (wave >> 1) * 64, wc = (wave & 1) * 64;
    const int ml = l & 15, quad = l >> 4;
    f32x4 acc[4][4];
    #pragma unroll
    for (int i=0;i<4;++i)
        #pragma unroll
        for (int j=0;j<4;++j) acc[i][j] = (f32x4){0.f,0.f,0.f,0.f};

    const int c0r = tid >> 1;
    const int c0s = (tid & 1) * 2;
    for (int k0 = 0; k0 < K; k0 += BK){
        uint4 av0 = *(const uint4*)&A [(bm + c0r)*K + k0 + c0s*8];
        uint4 av1 = *(const uint4*)&A [(bm + c0r)*K + k0 + c0s*8 + 8];
        uint4 bv0 = *(const uint4*)&Bt[(bn + c0r)*K + k0 + c0s*8];
        uint4 bv1 = *(const uint4*)&Bt[(bn + c0r)*K + k0 + c0s*8 + 8];
        __syncthreads();
        *(uint4*)&As[c0r*ASTR + c0s*8]     = av0;
        *(uint4*)&As[c0r*ASTR + c0s*8 + 8] = av1;
        *(uint4*)&Bs[c0r*ASTR + c0s*8]     = bv0;
        *(uint4*)&Bs[c0r*ASTR + c0s*8 + 8] = bv1;
        __syncthreads();
        short8 af[4], bfv[4];
        #pragma unroll
        for (int f=0; f<4; ++f){
            af[f]  = *(const short8*)&As[(wr + f*16 + ml)*ASTR + quad*8];
            bfv[f] = *(const short8*)&Bs[(wc + f*16 + ml)*ASTR + quad*8];
        }
        #pragma unroll
        for (int i=0;i<4;++i)
            #pragma unroll
            for (int j=0;j<4;++j)
                acc[i][j] = __builtin_amdgcn_mfma_f32_16x16x32_bf16(af[i], bfv[j], acc[i][j], 0,0,0);
    }
    #pragma unroll
    for (int i=0;i<4;++i){
        #pragma unroll
        for (int j=0;j<4;++j){
            const int gcol = bn + wc + j*16 + ml;
            const float bsv = bias[gcol];
            #pragma unroll
            for (int r=0;r<4;++r){
                const int grow = bm + wr + i*16 + quad*4 + r;
                float val = acc[i][j][r] + bsv;
                if (ACT == 2){
                    float v1 = __shfl_down(val, 1);
                    float v2 = __shfl_down(val, 2);
                    float v3 = __shfl_down(val, 3);
                    if ((l & 3) == 0){
                        int hd = gcol >> 2;
                        XCo[grow*HD + hd] = make_float2(val, v1);
                        float m2 = v2*v2 + v3*v3;
                        float s = sqrtf(m2)/(1.f + m2);
                        Ao[grow*HD + hd] = make_float2(v2*s, v3*s);
                    }
                } else if (ACT == 1){
                    val *= 1.f/(1.f + expf(-val));
                    Cb[grow*N + gcol] = f2bf(val);
                } else {
                    Cf[grow*N + gcol] = val;
                }
            }
        }
    }
}

// ---------- u[c] = Vinv_h @ (c==0 ? hidden : xc[c-1]),  c = 0..256 ----------
__global__ __launch_bounds__(256) void uext_kernel(const float2* __restrict__ Vinv,
                            const float* __restrict__ hre, const float* __restrict__ him,
                            const float2* __restrict__ XC, float2* __restrict__ Uext){
    int g = blockIdx.x*256 + threadIdx.x;
    int c = g >> 9;
    int hn = g & 511;
    int h = hn >> 6;
    const float2* vrow = &Vinv[hn*64];
    float2 acc = make_float2(0.f, 0.f);
    if (c == 0){
        #pragma unroll 8
        for (int o=0;o<64;++o){
            float2 x = make_float2(hre[h*64+o], him[h*64+o]);
            float2 p = cmul(vrow[o], x);
            acc.x += p.x; acc.y += p.y;
        }
    } else {
        const float2* xrow = &XC[(c-1)*HD + h*64];
        #pragma unroll 8
        for (int o=0;o<64;++o){
            float2 p = cmul(vrow[o], xrow[o]);
            acc.x += p.x; acc.y += p.y;
        }
    }
    Uext[g] = acc;
}

// ---------- sequential complex scan ----------
__global__ __launch_bounds__(512) void scan_kernel(const float2* __restrict__ Uext,
                            const float2* __restrict__ A, float2* __restrict__ S){
    int t = threadIdx.x;
    float2 st = Uext[t];
    for (int m = 0; m < LSEQ; ++m){
        float2 a = A[m*HD + t];
        float2 u = Uext[(m+1)*HD + t];
        float2 ns;
        ns.x = a.x*st.x - a.y*st.y + u.x;
        ns.y = a.x*st.y + a.y*st.x + u.y;
        st = ns;
        S[m*HD + t] = st;
    }
}

// ---------- h[m] = V_h @ S[m]; hr as bf16; fp32 tail ----------
__global__ __launch_bounds__(256) void vmul_kernel(const float* __restrict__ Vr,
                            const float* __restrict__ Vi,
                            const float2* __restrict__ S, ushort* __restrict__ hrb,
                            float* __restrict__ out_tail, int tail_n){
    int g = blockIdx.x*256 + threadIdx.x;
    int m = g >> 9, hn = g & 511;
    int h = hn >> 6;
    const float* vr = &Vr[hn*64];
    const float* vi = &Vi[hn*64];
    const float2* srow = &S[m*HD + h*64];
    float2 acc = make_float2(0.f, 0.f);
    #pragma unroll 8
    for (int o=0;o<64;++o){
        float2 v = make_float2(vr[o], vi[o]);
        float2 p = cmul(v, srow[o]);
        acc.x += p.x; acc.y += p.y;
    }
    hrb[m*DIMN + hn*2]   = f2bf(acc.x);
    hrb[m*DIMN + hn*2+1] = f2bf(acc.y);
    if (m == LSEQ-1){
        if (tail_n >= 1024){
            out_tail[hn]       = acc.x;
            out_tail[512 + hn] = acc.y;
        } else if (tail_n >= 512){
            out_tail[hn] = acc.x;
        }
    }
}

extern "C" void kernel_launch(void* const* d_in, const int* in_sizes, int n_in,
                              void* d_out, int out_size, void* d_ws, size_t ws_size,
                              hipStream_t stream) {
    const float* x      = (const float*)d_in[0];
    const float* hidr   = (const float*)d_in[1];
    const float* hidi   = (const float*)d_in[2];
    const float* w_in1  = (const float*)d_in[3];
    const float* b_in1  = (const float*)d_in[4];
    const float* w_in2  = (const float*)d_in[5];
    const float* b_in2  = (const float*)d_in[6];
    const float* w_out1 = (const float*)d_in[7];
    const float* b_out1 = (const float*)d_in[8];
    const float* w_out2 = (const float*)d_in[9];
    const float* b_out2 = (const float*)d_in[10];
    const float* Vr     = (const float*)d_in[11];
    const float* Vi     = (const float*)d_in[12];
    float* out = (float*)d_out;

    char* ws = (char*)d_ws;
    float2* Vinv  = (float2*)(ws + 0);          // 262144
    ushort* wt    = (ushort*)(ws + 262144);     // 4 MB, reused for all 4 weights
    ushort* x_bf  = (ushort*)(ws + 4456448);    // 512 KB, later reused as y1_bf
    ushort* t1_bf = (ushort*)(ws + 4980736);    // 512 KB, later reused as hr_bf
    float2* XC    = (float2*)(ws + 5505024);    // 1 MB, later reused as S
    float2* Aseq  = (float2*)(ws + 6553600);    // 1 MB
    float2* Uext  = (float2*)(ws + 7602176);    // 1052672
    ushort* y1_bf = x_bf;
    ushort* hr_bf = t1_bf;
    float2* S     = XC;

    const int tail_n = out_size - LSEQ*DIMN;

    inv_kernel<<<NH, 512, 0, stream>>>(Vr, Vi, Vinv);

    cvt_bf16_kernel<<<LSEQ*DIMN/4/256, 256, 0, stream>>>(x, x_bf, LSEQ*DIMN/4);
    transpose_cvt<<<dim3(32,32), 256, 0, stream>>>(w_in1, wt, DIMN, DIMN);
    gemm_bt<1><<<dim3(8,2), 256, 0, stream>>>(x_bf, wt, b_in1, nullptr, t1_bf,
                                              nullptr, nullptr, LSEQ, DIMN, DIMN);
    transpose_cvt<<<dim3(64,32), 256, 0, stream>>>(w_in2, wt, DIMN, 2048);
    gemm_bt<2><<<dim3(16,2), 256, 0, stream>>>(t1_bf, wt, b_in2, nullptr, nullptr,
                                               XC, Aseq, LSEQ, 2048, DIMN);
    uext_kernel<<<(LSEQ+1)*HD/256, 256, 0, stream>>>(Vinv, hidr, hidi, XC, Uext);
    scan_kernel<<<1, 512, 0, stream>>>(Uext, Aseq, S);
    vmul_kernel<<<LSEQ*HD/256, 256, 0, stream>>>(Vr, Vi, S, hr_bf, out + LSEQ*DIMN, tail_n);
    transpose_cvt<<<dim3(32,32), 256, 0, stream>>>(w_out1, wt, DIMN, DIMN);
    gemm_bt<1><<<dim3(8,2), 256, 0, stream>>>(hr_bf, wt, b_out1, nullptr, y1_bf,
                                              nullptr, nullptr, LSEQ, DIMN, DIMN);
    transpose_cvt<<<dim3(32,32), 256, 0, stream>>>(w_out2, wt, DIMN, DIMN);
    gemm_bt<0><<<dim3(8,2), 256, 0, stream>>>(y1_bf, wt, b_out2, out, nullptr,
                                              nullptr, nullptr, LSEQ, DIMN, DIMN);
}

// Round 8
// 357.393 us; speedup vs baseline: 1.4689x; 1.0738x over previous
//
#include <hip/hip_runtime.h>
#include <math.h>

#define DIMN 1024
#define NH 8
#define ND 64
#define LSEQ 256
#define HD 512      // NH*ND

typedef __attribute__((ext_vector_type(8))) short short8;
typedef __attribute__((ext_vector_type(4))) float f32x4;

__device__ __forceinline__ float2 cmul(float2 a, float2 b){
    return make_float2(a.x*b.x - a.y*b.y, a.x*b.y + a.y*b.x);
}
__device__ __forceinline__ ushort f2bf(float f){
    union { float f; unsigned u; } v; v.f = f;
    unsigned r = v.u + 0x7FFF + ((v.u >> 16) & 1);   // RNE
    return (ushort)(r >> 16);
}

// ---------- complex 64x64 inverse per head: IN-PLACE Gauss-Jordan, width 64 ----------
// LDS-throughput-bound per CU (R7 analysis) -> halve LDS ops by dropping the
// augmented half. In-place GJ (verified on 2x2): p=1/a[k][k]; row k *= p,
// a[k][k]=p; for i!=k: f=a[i][k]; a[i][j!=k] -= f*a[k][j]; a[i][k] = -f*p.
// Lane k's update is branch-free: v0 := (l==k ? 0 : a[r][l]); v = v0 - f*spr.
// Wave w owns rows 8w..8w+7; lane l owns col l. 2 barriers/step, stride 65.
#define ISTR 65
__global__ __launch_bounds__(512) void inv_kernel(const float* __restrict__ Vr,
                                                  const float* __restrict__ Vi,
                                                  float2* __restrict__ Vinv){
    __shared__ float2 Mx[64*ISTR];
    const int h = blockIdx.x;
    const int tid = threadIdx.x;
    for (int idx = tid; idx < 4096; idx += 512){
        int i = idx >> 6, j = idx & 63;
        Mx[i*ISTR + j] = make_float2(Vr[h*4096 + idx], Vi[h*4096 + idx]);
    }
    __syncthreads();
    const int w = tid >> 6, l = tid & 63;
    const int rbase = w*8;
    for (int k = 0; k < 64; ++k){
        // ---- phase A: read everything pre-update ----
        float2 d = Mx[k*ISTR + k];                    // broadcast read
        float im = 1.f/(d.x*d.x + d.y*d.y);
        float2 p = make_float2(d.x*im, -d.y*im);
        float2 prl = Mx[k*ISTR + l];                  // pivot row, my column
        float2 spr = (l == k) ? p : cmul(prl, p);     // scaled pivot row entry
        float2 fv[8];
        #pragma unroll
        for (int rr = 0; rr < 8; ++rr)
            fv[rr] = Mx[(rbase+rr)*ISTR + k];         // broadcast reads
        __syncthreads();
        // ---- phase B: in-place update; owner-only writes ----
        #pragma unroll
        for (int rr = 0; rr < 8; ++rr){
            int r = rbase + rr;
            if (r == k){                               // wave-uniform branch
                Mx[r*ISTR + l] = spr;
            } else {
                float2 f  = fv[rr];
                float2 v0 = Mx[r*ISTR + l];
                if (l == k){ v0.x = 0.f; v0.y = 0.f; } // select, no divergence cost
                v0.x -= f.x*spr.x - f.y*spr.y;
                v0.y -= f.x*spr.y + f.y*spr.x;
                Mx[r*ISTR + l] = v0;
            }
        }
        __syncthreads();
    }
    for (int idx = tid; idx < 4096; idx += 512){
        int i = idx >> 6, j = idx & 63;
        Vinv[h*4096 + idx] = Mx[i*ISTR + j];
    }
}

// ---------- W (K x N fp32) -> Wt (N x K bf16) transpose+convert ----------
__global__ __launch_bounds__(256) void transpose_cvt(const float* __restrict__ W,
                 ushort* __restrict__ Wt, int K, int N){
    __shared__ float tile[32][33];
    const int n0 = blockIdx.x * 32, k0 = blockIdx.y * 32;
    const int tx = threadIdx.x & 31, ty = threadIdx.x >> 5;   // ty 0..7
    #pragma unroll
    for (int i = 0; i < 4; ++i)
        tile[ty + i*8][tx] = W[(k0 + ty + i*8)*N + n0 + tx];
    __syncthreads();
    #pragma unroll
    for (int i = 0; i < 4; ++i){
        int r = ty + i*8;
        Wt[(n0 + r)*K + k0 + tx] = f2bf(tile[tx][r]);
    }
}

// ---------- fp32 -> bf16 elementwise (x) ----------
__global__ __launch_bounds__(256) void cvt_bf16_kernel(const float* __restrict__ in,
                                 ushort* __restrict__ o, int n4){
    int i = blockIdx.x*256 + threadIdx.x;
    if (i < n4){
        float4 v = ((const float4*)in)[i];
        ushort4 u; u.x=f2bf(v.x); u.y=f2bf(v.y); u.z=f2bf(v.z); u.w=f2bf(v.w);
        ((ushort4*)o)[i] = u;
    }
}

// ---------- bf16 MFMA GEMM: C(MxN) = act(A(MxK) @ Bt(NxK)^T + bias) ----------
#define BM 128
#define BN 128
#define BK 32
#define ASTR 40
template<int ACT>
__global__ __launch_bounds__(256) void gemm_bt(const ushort* __restrict__ A,
                 const ushort* __restrict__ Bt, const float* __restrict__ bias,
                 float* __restrict__ Cf, ushort* __restrict__ Cb,
                 float2* __restrict__ XCo, float2* __restrict__ Ao,
                 int M, int N, int K){
    __shared__ ushort As[BM*ASTR];
    __shared__ ushort Bs[BN*ASTR];
    const int tid = threadIdx.x;
    const int bm = blockIdx.y * BM, bn = blockIdx.x * BN;
    const int wave = tid >> 6, l = tid & 63;
    const int wr = (wave >> 1) * 64, wc = (wave & 1) * 64;
    const int ml = l & 15, quad = l >> 4;
    f32x4 acc[4][4];
    #pragma unroll
    for (int i=0;i<4;++i)
        #pragma unroll
        for (int j=0;j<4;++j) acc[i][j] = (f32x4){0.f,0.f,0.f,0.f};

    const int c0r = tid >> 1;
    const int c0s = (tid & 1) * 2;
    for (int k0 = 0; k0 < K; k0 += BK){
        uint4 av0 = *(const uint4*)&A [(bm + c0r)*K + k0 + c0s*8];
        uint4 av1 = *(const uint4*)&A [(bm + c0r)*K + k0 + c0s*8 + 8];
        uint4 bv0 = *(const uint4*)&Bt[(bn + c0r)*K + k0 + c0s*8];
        uint4 bv1 = *(const uint4*)&Bt[(bn + c0r)*K + k0 + c0s*8 + 8];
        __syncthreads();
        *(uint4*)&As[c0r*ASTR + c0s*8]     = av0;
        *(uint4*)&As[c0r*ASTR + c0s*8 + 8] = av1;
        *(uint4*)&Bs[c0r*ASTR + c0s*8]     = bv0;
        *(uint4*)&Bs[c0r*ASTR + c0s*8 + 8] = bv1;
        __syncthreads();
        short8 af[4], bfv[4];
        #pragma unroll
        for (int f=0; f<4; ++f){
            af[f]  = *(const short8*)&As[(wr + f*16 + ml)*ASTR + quad*8];
            bfv[f] = *(const short8*)&Bs[(wc + f*16 + ml)*ASTR + quad*8];
        }
        #pragma unroll
        for (int i=0;i<4;++i)
            #pragma unroll
            for (int j=0;j<4;++j)
                acc[i][j] = __builtin_amdgcn_mfma_f32_16x16x32_bf16(af[i], bfv[j], acc[i][j], 0,0,0);
    }
    #pragma unroll
    for (int i=0;i<4;++i){
        #pragma unroll
        for (int j=0;j<4;++j){
            const int gcol = bn + wc + j*16 + ml;
            const float bsv = bias[gcol];
            #pragma unroll
            for (int r=0;r<4;++r){
                const int grow = bm + wr + i*16 + quad*4 + r;
                float val = acc[i][j][r] + bsv;
                if (ACT == 2){
                    float v1 = __shfl_down(val, 1);
                    float v2 = __shfl_down(val, 2);
                    float v3 = __shfl_down(val, 3);
                    if ((l & 3) == 0){
                        int hd = gcol >> 2;
                        XCo[grow*HD + hd] = make_float2(val, v1);
                        float m2 = v2*v2 + v3*v3;
                        float s = sqrtf(m2)/(1.f + m2);
                        Ao[grow*HD + hd] = make_float2(v2*s, v3*s);
                    }
                } else if (ACT == 1){
                    val *= 1.f/(1.f + expf(-val));
                    Cb[grow*N + gcol] = f2bf(val);
                } else {
                    Cf[grow*N + gcol] = val;
                }
            }
        }
    }
}

// ---------- u[c] = Vinv_h @ (c==0 ? hidden : xc[c-1]),  c = 0..256 ----------
__global__ __launch_bounds__(256) void uext_kernel(const float2* __restrict__ Vinv,
                            const float* __restrict__ hre, const float* __restrict__ him,
                            const float2* __restrict__ XC, float2* __restrict__ Uext){
    int g = blockIdx.x*256 + threadIdx.x;
    int c = g >> 9;
    int hn = g & 511;
    int h = hn >> 6;
    const float2* vrow = &Vinv[hn*64];
    float2 acc = make_float2(0.f, 0.f);
    if (c == 0){
        #pragma unroll 8
        for (int o=0;o<64;++o){
            float2 x = make_float2(hre[h*64+o], him[h*64+o]);
            float2 p = cmul(vrow[o], x);
            acc.x += p.x; acc.y += p.y;
        }
    } else {
        const float2* xrow = &XC[(c-1)*HD + h*64];
        #pragma unroll 8
        for (int o=0;o<64;++o){
            float2 p = cmul(vrow[o], xrow[o]);
            acc.x += p.x; acc.y += p.y;
        }
    }
    Uext[g] = acc;
}

// ---------- sequential complex scan ----------
__global__ __launch_bounds__(512) void scan_kernel(const float2* __restrict__ Uext,
                            const float2* __restrict__ A, float2* __restrict__ S){
    int t = threadIdx.x;
    float2 st = Uext[t];
    for (int m = 0; m < LSEQ; ++m){
        float2 a = A[m*HD + t];
        float2 u = Uext[(m+1)*HD + t];
        float2 ns;
        ns.x = a.x*st.x - a.y*st.y + u.x;
        ns.y = a.x*st.y + a.y*st.x + u.y;
        st = ns;
        S[m*HD + t] = st;
    }
}

// ---------- h[m] = V_h @ S[m]; hr as bf16; fp32 tail ----------
__global__ __launch_bounds__(256) void vmul_kernel(const float* __restrict__ Vr,
                            const float* __restrict__ Vi,
                            const float2* __restrict__ S, ushort* __restrict__ hrb,
                            float* __restrict__ out_tail, int tail_n){
    int g = blockIdx.x*256 + threadIdx.x;
    int m = g >> 9, hn = g & 511;
    int h = hn >> 6;
    const float* vr = &Vr[hn*64];
    const float* vi = &Vi[hn*64];
    const float2* srow = &S[m*HD + h*64];
    float2 acc = make_float2(0.f, 0.f);
    #pragma unroll 8
    for (int o=0;o<64;++o){
        float2 v = make_float2(vr[o], vi[o]);
        float2 p = cmul(v, srow[o]);
        acc.x += p.x; acc.y += p.y;
    }
    hrb[m*DIMN + hn*2]   = f2bf(acc.x);
    hrb[m*DIMN + hn*2+1] = f2bf(acc.y);
    if (m == LSEQ-1){
        if (tail_n >= 1024){
            out_tail[hn]       = acc.x;
            out_tail[512 + hn] = acc.y;
        } else if (tail_n >= 512){
            out_tail[hn] = acc.x;
        }
    }
}

extern "C" void kernel_launch(void* const* d_in, const int* in_sizes, int n_in,
                              void* d_out, int out_size, void* d_ws, size_t ws_size,
                              hipStream_t stream) {
    const float* x      = (const float*)d_in[0];
    const float* hidr   = (const float*)d_in[1];
    const float* hidi   = (const float*)d_in[2];
    const float* w_in1  = (const float*)d_in[3];
    const float* b_in1  = (const float*)d_in[4];
    const float* w_in2  = (const float*)d_in[5];
    const float* b_in2  = (const float*)d_in[6];
    const float* w_out1 = (const float*)d_in[7];
    const float* b_out1 = (const float*)d_in[8];
    const float* w_out2 = (const float*)d_in[9];
    const float* b_out2 = (const float*)d_in[10];
    const float* Vr     = (const float*)d_in[11];
    const float* Vi     = (const float*)d_in[12];
    float* out = (float*)d_out;

    char* ws = (char*)d_ws;
    float2* Vinv  = (float2*)(ws + 0);          // 262144
    ushort* wt    = (ushort*)(ws + 262144);     // 4 MB, reused for all 4 weights
    ushort* x_bf  = (ushort*)(ws + 4456448);    // 512 KB, later reused as y1_bf
    ushort* t1_bf = (ushort*)(ws + 4980736);    // 512 KB, later reused as hr_bf
    float2* XC    = (float2*)(ws + 5505024);    // 1 MB, later reused as S
    float2* Aseq  = (float2*)(ws + 6553600);    // 1 MB
    float2* Uext  = (float2*)(ws + 7602176);    // 1052672
    ushort* y1_bf = x_bf;
    ushort* hr_bf = t1_bf;
    float2* S     = XC;

    const int tail_n = out_size - LSEQ*DIMN;

    inv_kernel<<<NH, 512, 0, stream>>>(Vr, Vi, Vinv);

    cvt_bf16_kernel<<<LSEQ*DIMN/4/256, 256, 0, stream>>>(x, x_bf, LSEQ*DIMN/4);
    transpose_cvt<<<dim3(32,32), 256, 0, stream>>>(w_in1, wt, DIMN, DIMN);
    gemm_bt<1><<<dim3(8,2), 256, 0, stream>>>(x_bf, wt, b_in1, nullptr, t1_bf,
                                              nullptr, nullptr, LSEQ, DIMN, DIMN);
    transpose_cvt<<<dim3(64,32), 256, 0, stream>>>(w_in2, wt, DIMN, 2048);
    gemm_bt<2><<<dim3(16,2), 256, 0, stream>>>(t1_bf, wt, b_in2, nullptr, nullptr,
                                               XC, Aseq, LSEQ, 2048, DIMN);
    uext_kernel<<<(LSEQ+1)*HD/256, 256, 0, stream>>>(Vinv, hidr, hidi, XC, Uext);
    scan_kernel<<<1, 512, 0, stream>>>(Uext, Aseq, S);
    vmul_kernel<<<LSEQ*HD/256, 256, 0, stream>>>(Vr, Vi, S, hr_bf, out + LSEQ*DIMN, tail_n);
    transpose_cvt<<<dim3(32,32), 256, 0, stream>>>(w_out1, wt, DIMN, DIMN);
    gemm_bt<1><<<dim3(8,2), 256, 0, stream>>>(hr_bf, wt, b_out1, nullptr, y1_bf,
                                              nullptr, nullptr, LSEQ, DIMN, DIMN);
    transpose_cvt<<<dim3(32,32), 256, 0, stream>>>(w_out2, wt, DIMN, DIMN);
    gemm_bt<0><<<dim3(8,2), 256, 0, stream>>>(y1_bf, wt, b_out2, out, nullptr,
                                              nullptr, nullptr, LSEQ, DIMN, DIMN);
}

// Round 9
// 344.373 us; speedup vs baseline: 1.5244x; 1.0378x over previous
//
#include <hip/hip_runtime.h>
#include <math.h>

#define DIMN 1024
#define NH 8
#define ND 64
#define LSEQ 256
#define HD 512      // NH*ND

typedef __attribute__((ext_vector_type(8))) short short8;
typedef __attribute__((ext_vector_type(4))) float f32x4;

__device__ __forceinline__ float2 cmul(float2 a, float2 b){
    return make_float2(a.x*b.x - a.y*b.y, a.x*b.y + a.y*b.x);
}
__device__ __forceinline__ ushort f2bf(float f){
    union { float f; unsigned u; } v; v.f = f;
    unsigned r = v.u + 0x7FFF + ((v.u >> 16) & 1);   // RNE
    return (ushort)(r >> 16);
}

#define ISTR 65

// ---------- fused prep: blocks 0-7 = per-head inverse (R8 in-place GJ);
// blocks 8-135 = x->bf16 cast; blocks 136+ = weight transposes (2 tiles/blk).
// All jobs are mutually independent => co-scheduled across CUs in ONE dispatch,
// hiding the 8-CU inv behind the bandwidth-bound transpose work.
__global__ __launch_bounds__(512) void prep_kernel(
        const float* __restrict__ x,
        const float* __restrict__ w1, const float* __restrict__ w2,
        const float* __restrict__ w3, const float* __restrict__ w4,
        const float* __restrict__ Vr, const float* __restrict__ Vi,
        ushort* __restrict__ x_bf,
        ushort* __restrict__ w1t, ushort* __restrict__ w2t,
        ushort* __restrict__ w3t, ushort* __restrict__ w4t,
        float2* __restrict__ Vinv){
    __shared__ float2 Mx[64*ISTR];          // 33280 B; transposes alias as float*
    const int b = blockIdx.x;
    const int tid = threadIdx.x;

    if (b < 8){
        // ---- in-place Gauss-Jordan inverse, head b (R8 body, verbatim) ----
        const int h = b;
        for (int idx = tid; idx < 4096; idx += 512){
            int i = idx >> 6, j = idx & 63;
            Mx[i*ISTR + j] = make_float2(Vr[h*4096 + idx], Vi[h*4096 + idx]);
        }
        __syncthreads();
        const int w = tid >> 6, l = tid & 63;
        const int rbase = w*8;
        for (int k = 0; k < 64; ++k){
            float2 d = Mx[k*ISTR + k];
            float im = 1.f/(d.x*d.x + d.y*d.y);
            float2 p = make_float2(d.x*im, -d.y*im);
            float2 prl = Mx[k*ISTR + l];
            float2 spr = (l == k) ? p : cmul(prl, p);
            float2 fv[8];
            #pragma unroll
            for (int rr = 0; rr < 8; ++rr)
                fv[rr] = Mx[(rbase+rr)*ISTR + k];
            __syncthreads();
            #pragma unroll
            for (int rr = 0; rr < 8; ++rr){
                int r = rbase + rr;
                if (r == k){
                    Mx[r*ISTR + l] = spr;
                } else {
                    float2 f  = fv[rr];
                    float2 v0 = Mx[r*ISTR + l];
                    if (l == k){ v0.x = 0.f; v0.y = 0.f; }
                    v0.x -= f.x*spr.x - f.y*spr.y;
                    v0.y -= f.x*spr.y + f.y*spr.x;
                    Mx[r*ISTR + l] = v0;
                }
            }
            __syncthreads();
        }
        for (int idx = tid; idx < 4096; idx += 512){
            int i = idx >> 6, j = idx & 63;
            Vinv[h*4096 + idx] = Mx[i*ISTR + j];
        }
        return;
    }

    int widx = b - 8;
    if (widx < 128){
        // ---- x -> bf16: 65536 float4s total ----
        int i = widx*512 + tid;
        float4 v = ((const float4*)x)[i];
        ushort4 u; u.x=f2bf(v.x); u.y=f2bf(v.y); u.z=f2bf(v.z); u.w=f2bf(v.w);
        ((ushort4*)x_bf)[i] = u;
        return;
    }
    widx -= 128;

    // ---- weight transpose+convert, two 32x32 tiles per block ----
    const float* W; ushort* Wt; int K = 1024, N;
    if (widx < 512)            { W = w1; Wt = w1t; N = 1024; }
    else if (widx < 1536)      { W = w2; Wt = w2t; N = 2048; widx -= 512; }
    else if (widx < 2048)      { W = w3; Wt = w3t; N = 1024; widx -= 1536; }
    else                       { W = w4; Wt = w4t; N = 1024; widx -= 2048; }
    const int half = tid >> 8;                     // 0/1: which tile
    const int t = widx*2 + half;
    const int tiles_n = N >> 5;
    const int n0 = (t % tiles_n) * 32, k0 = (t / tiles_n) * 32;
    float* tile = (float*)Mx + half*(32*33);
    const int tx = tid & 31, ty = (tid >> 5) & 7;  // 32 x 8 within half
    #pragma unroll
    for (int i = 0; i < 4; ++i)
        tile[(ty + i*8)*33 + tx] = W[(k0 + ty + i*8)*N + n0 + tx];
    __syncthreads();
    #pragma unroll
    for (int i = 0; i < 4; ++i){
        int r = ty + i*8;
        Wt[(n0 + r)*K + k0 + tx] = f2bf(tile[tx*33 + r]);
    }
}

// ---------- serial-fallback kernels (used only if ws too small) ----------
__global__ __launch_bounds__(512) void inv_kernel(const float* __restrict__ Vr,
                                                  const float* __restrict__ Vi,
                                                  float2* __restrict__ Vinv){
    __shared__ float2 Mx[64*ISTR];
    const int h = blockIdx.x;
    const int tid = threadIdx.x;
    for (int idx = tid; idx < 4096; idx += 512){
        int i = idx >> 6, j = idx & 63;
        Mx[i*ISTR + j] = make_float2(Vr[h*4096 + idx], Vi[h*4096 + idx]);
    }
    __syncthreads();
    const int w = tid >> 6, l = tid & 63;
    const int rbase = w*8;
    for (int k = 0; k < 64; ++k){
        float2 d = Mx[k*ISTR + k];
        float im = 1.f/(d.x*d.x + d.y*d.y);
        float2 p = make_float2(d.x*im, -d.y*im);
        float2 prl = Mx[k*ISTR + l];
        float2 spr = (l == k) ? p : cmul(prl, p);
        float2 fv[8];
        #pragma unroll
        for (int rr = 0; rr < 8; ++rr)
            fv[rr] = Mx[(rbase+rr)*ISTR + k];
        __syncthreads();
        #pragma unroll
        for (int rr = 0; rr < 8; ++rr){
            int r = rbase + rr;
            if (r == k){
                Mx[r*ISTR + l] = spr;
            } else {
                float2 f  = fv[rr];
                float2 v0 = Mx[r*ISTR + l];
                if (l == k){ v0.x = 0.f; v0.y = 0.f; }
                v0.x -= f.x*spr.x - f.y*spr.y;
                v0.y -= f.x*spr.y + f.y*spr.x;
                Mx[r*ISTR + l] = v0;
            }
        }
        __syncthreads();
    }
    for (int idx = tid; idx < 4096; idx += 512){
        int i = idx >> 6, j = idx & 63;
        Vinv[h*4096 + idx] = Mx[i*ISTR + j];
    }
}

__global__ __launch_bounds__(256) void transpose_cvt(const float* __restrict__ W,
                 ushort* __restrict__ Wt, int K, int N){
    __shared__ float tile[32][33];
    const int n0 = blockIdx.x * 32, k0 = blockIdx.y * 32;
    const int tx = threadIdx.x & 31, ty = threadIdx.x >> 5;
    #pragma unroll
    for (int i = 0; i < 4; ++i)
        tile[ty + i*8][tx] = W[(k0 + ty + i*8)*N + n0 + tx];
    __syncthreads();
    #pragma unroll
    for (int i = 0; i < 4; ++i){
        int r = ty + i*8;
        Wt[(n0 + r)*K + k0 + tx] = f2bf(tile[tx][r]);
    }
}

__global__ __launch_bounds__(256) void cvt_bf16_kernel(const float* __restrict__ in,
                                 ushort* __restrict__ o, int n4){
    int i = blockIdx.x*256 + threadIdx.x;
    if (i < n4){
        float4 v = ((const float4*)in)[i];
        ushort4 u; u.x=f2bf(v.x); u.y=f2bf(v.y); u.z=f2bf(v.z); u.w=f2bf(v.w);
        ((ushort4*)o)[i] = u;
    }
}

// ---------- bf16 MFMA GEMM: C(MxN) = act(A(MxK) @ Bt(NxK)^T + bias) ----------
#define BM 128
#define BN 128
#define BK 32
#define ASTR 40
template<int ACT>
__global__ __launch_bounds__(256) void gemm_bt(const ushort* __restrict__ A,
                 const ushort* __restrict__ Bt, const float* __restrict__ bias,
                 float* __restrict__ Cf, ushort* __restrict__ Cb,
                 float2* __restrict__ XCo, float2* __restrict__ Ao,
                 int M, int N, int K){
    __shared__ ushort As[BM*ASTR];
    __shared__ ushort Bs[BN*ASTR];
    const int tid = threadIdx.x;
    const int bm = blockIdx.y * BM, bn = blockIdx.x * BN;
    const int wave = tid >> 6, l = tid & 63;
    const int wr = (wave >> 1) * 64, wc = (wave & 1) * 64;
    const int ml = l & 15, quad = l >> 4;
    f32x4 acc[4][4];
    #pragma unroll
    for (int i=0;i<4;++i)
        #pragma unroll
        for (int j=0;j<4;++j) acc[i][j] = (f32x4){0.f,0.f,0.f,0.f};

    const int c0r = tid >> 1;
    const int c0s = (tid & 1) * 2;
    for (int k0 = 0; k0 < K; k0 += BK){
        uint4 av0 = *(const uint4*)&A [(bm + c0r)*K + k0 + c0s*8];
        uint4 av1 = *(const uint4*)&A [(bm + c0r)*K + k0 + c0s*8 + 8];
        uint4 bv0 = *(const uint4*)&Bt[(bn + c0r)*K + k0 + c0s*8];
        uint4 bv1 = *(const uint4*)&Bt[(bn + c0r)*K + k0 + c0s*8 + 8];
        __syncthreads();
        *(uint4*)&As[c0r*ASTR + c0s*8]     = av0;
        *(uint4*)&As[c0r*ASTR + c0s*8 + 8] = av1;
        *(uint4*)&Bs[c0r*ASTR + c0s*8]     = bv0;
        *(uint4*)&Bs[c0r*ASTR + c0s*8 + 8] = bv1;
        __syncthreads();
        short8 af[4], bfv[4];
        #pragma unroll
        for (int f=0; f<4; ++f){
            af[f]  = *(const short8*)&As[(wr + f*16 + ml)*ASTR + quad*8];
            bfv[f] = *(const short8*)&Bs[(wc + f*16 + ml)*ASTR + quad*8];
        }
        #pragma unroll
        for (int i=0;i<4;++i)
            #pragma unroll
            for (int j=0;j<4;++j)
                acc[i][j] = __builtin_amdgcn_mfma_f32_16x16x32_bf16(af[i], bfv[j], acc[i][j], 0,0,0);
    }
    #pragma unroll
    for (int i=0;i<4;++i){
        #pragma unroll
        for (int j=0;j<4;++j){
            const int gcol = bn + wc + j*16 + ml;
            const float bsv = bias[gcol];
            #pragma unroll
            for (int r=0;r<4;++r){
                const int grow = bm + wr + i*16 + quad*4 + r;
                float val = acc[i][j][r] + bsv;
                if (ACT == 2){
                    float v1 = __shfl_down(val, 1);
                    float v2 = __shfl_down(val, 2);
                    float v3 = __shfl_down(val, 3);
                    if ((l & 3) == 0){
                        int hd = gcol >> 2;
                        XCo[grow*HD + hd] = make_float2(val, v1);
                        float m2 = v2*v2 + v3*v3;
                        float s = sqrtf(m2)/(1.f + m2);
                        Ao[grow*HD + hd] = make_float2(v2*s, v3*s);
                    }
                } else if (ACT == 1){
                    val *= 1.f/(1.f + expf(-val));
                    Cb[grow*N + gcol] = f2bf(val);
                } else {
                    Cf[grow*N + gcol] = val;
                }
            }
        }
    }
}

// ---------- u[c] = Vinv_h @ (c==0 ? hidden : xc[c-1]),  c = 0..256 ----------
__global__ __launch_bounds__(256) void uext_kernel(const float2* __restrict__ Vinv,
                            const float* __restrict__ hre, const float* __restrict__ him,
                            const float2* __restrict__ XC, float2* __restrict__ Uext){
    int g = blockIdx.x*256 + threadIdx.x;
    int c = g >> 9;
    int hn = g & 511;
    int h = hn >> 6;
    const float2* vrow = &Vinv[hn*64];
    float2 acc = make_float2(0.f, 0.f);
    if (c == 0){
        #pragma unroll 8
        for (int o=0;o<64;++o){
            float2 x = make_float2(hre[h*64+o], him[h*64+o]);
            float2 p = cmul(vrow[o], x);
            acc.x += p.x; acc.y += p.y;
        }
    } else {
        const float2* xrow = &XC[(c-1)*HD + h*64];
        #pragma unroll 8
        for (int o=0;o<64;++o){
            float2 p = cmul(vrow[o], xrow[o]);
            acc.x += p.x; acc.y += p.y;
        }
    }
    Uext[g] = acc;
}

// ---------- sequential complex scan ----------
__global__ __launch_bounds__(512) void scan_kernel(const float2* __restrict__ Uext,
                            const float2* __restrict__ A, float2* __restrict__ S){
    int t = threadIdx.x;
    float2 st = Uext[t];
    for (int m = 0; m < LSEQ; ++m){
        float2 a = A[m*HD + t];
        float2 u = Uext[(m+1)*HD + t];
        float2 ns;
        ns.x = a.x*st.x - a.y*st.y + u.x;
        ns.y = a.x*st.y + a.y*st.x + u.y;
        st = ns;
        S[m*HD + t] = st;
    }
}

// ---------- h[m] = V_h @ S[m]; hr as bf16; fp32 tail ----------
__global__ __launch_bounds__(256) void vmul_kernel(const float* __restrict__ Vr,
                            const float* __restrict__ Vi,
                            const float2* __restrict__ S, ushort* __restrict__ hrb,
                            float* __restrict__ out_tail, int tail_n){
    int g = blockIdx.x*256 + threadIdx.x;
    int m = g >> 9, hn = g & 511;
    int h = hn >> 6;
    const float* vr = &Vr[hn*64];
    const float* vi = &Vi[hn*64];
    const float2* srow = &S[m*HD + h*64];
    float2 acc = make_float2(0.f, 0.f);
    #pragma unroll 8
    for (int o=0;o<64;++o){
        float2 v = make_float2(vr[o], vi[o]);
        float2 p = cmul(v, srow[o]);
        acc.x += p.x; acc.y += p.y;
    }
    hrb[m*DIMN + hn*2]   = f2bf(acc.x);
    hrb[m*DIMN + hn*2+1] = f2bf(acc.y);
    if (m == LSEQ-1){
        if (tail_n >= 1024){
            out_tail[hn]       = acc.x;
            out_tail[512 + hn] = acc.y;
        } else if (tail_n >= 512){
            out_tail[hn] = acc.x;
        }
    }
}

extern "C" void kernel_launch(void* const* d_in, const int* in_sizes, int n_in,
                              void* d_out, int out_size, void* d_ws, size_t ws_size,
                              hipStream_t stream) {
    const float* x      = (const float*)d_in[0];
    const float* hidr   = (const float*)d_in[1];
    const float* hidi   = (const float*)d_in[2];
    const float* w_in1  = (const float*)d_in[3];
    const float* b_in1  = (const float*)d_in[4];
    const float* w_in2  = (const float*)d_in[5];
    const float* b_in2  = (const float*)d_in[6];
    const float* w_out1 = (const float*)d_in[7];
    const float* b_out1 = (const float*)d_in[8];
    const float* w_out2 = (const float*)d_in[9];
    const float* b_out2 = (const float*)d_in[10];
    const float* Vr     = (const float*)d_in[11];
    const float* Vi     = (const float*)d_in[12];
    float* out = (float*)d_out;
    const int tail_n = out_size - LSEQ*DIMN;
    char* ws = (char*)d_ws;

    if (ws_size >= 14946304u){
        // ---- fused-prep layout: each transposed weight gets its own buffer ----
        float2* Vinv  = (float2*)(ws + 0);          // 262144
        ushort* w1t   = (ushort*)(ws + 262144);     // 2 MB
        ushort* w2t   = (ushort*)(ws + 2359296);    // 4 MB
        ushort* w3t   = (ushort*)(ws + 6553600);    // 2 MB
        ushort* w4t   = (ushort*)(ws + 8650752);    // 2 MB
        ushort* x_bf  = (ushort*)(ws + 10747904);   // 512 KB (reused as y1_bf)
        ushort* t1_bf = (ushort*)(ws + 11272192);   // 512 KB (reused as hr_bf)
        float2* XC    = (float2*)(ws + 11796480);   // 1 MB (reused as S)
        float2* Aseq  = (float2*)(ws + 12845056);   // 1 MB
        float2* Uext  = (float2*)(ws + 13893632);   // 1052672
        ushort* y1_bf = x_bf;
        ushort* hr_bf = t1_bf;
        float2* S     = XC;

        prep_kernel<<<2696, 512, 0, stream>>>(x, w_in1, w_in2, w_out1, w_out2,
                                              Vr, Vi, x_bf, w1t, w2t, w3t, w4t, Vinv);
        gemm_bt<1><<<dim3(8,2), 256, 0, stream>>>(x_bf, w1t, b_in1, nullptr, t1_bf,
                                                  nullptr, nullptr, LSEQ, DIMN, DIMN);
        gemm_bt<2><<<dim3(16,2), 256, 0, stream>>>(t1_bf, w2t, b_in2, nullptr, nullptr,
                                                   XC, Aseq, LSEQ, 2048, DIMN);
        uext_kernel<<<(LSEQ+1)*HD/256, 256, 0, stream>>>(Vinv, hidr, hidi, XC, Uext);
        scan_kernel<<<1, 512, 0, stream>>>(Uext, Aseq, S);
        vmul_kernel<<<LSEQ*HD/256, 256, 0, stream>>>(Vr, Vi, S, hr_bf, out + LSEQ*DIMN, tail_n);
        gemm_bt<1><<<dim3(8,2), 256, 0, stream>>>(hr_bf, w3t, b_out1, nullptr, y1_bf,
                                                  nullptr, nullptr, LSEQ, DIMN, DIMN);
        gemm_bt<0><<<dim3(8,2), 256, 0, stream>>>(y1_bf, w4t, b_out2, out, nullptr,
                                                  nullptr, nullptr, LSEQ, DIMN, DIMN);
    } else {
        // ---- fallback: R8 serial path with single reused weight buffer ----
        float2* Vinv  = (float2*)(ws + 0);
        ushort* wt    = (ushort*)(ws + 262144);
        ushort* x_bf  = (ushort*)(ws + 4456448);
        ushort* t1_bf = (ushort*)(ws + 4980736);
        float2* XC    = (float2*)(ws + 5505024);
        float2* Aseq  = (float2*)(ws + 6553600);
        float2* Uext  = (float2*)(ws + 7602176);
        ushort* y1_bf = x_bf;
        ushort* hr_bf = t1_bf;
        float2* S     = XC;

        inv_kernel<<<NH, 512, 0, stream>>>(Vr, Vi, Vinv);
        cvt_bf16_kernel<<<LSEQ*DIMN/4/256, 256, 0, stream>>>(x, x_bf, LSEQ*DIMN/4);
        transpose_cvt<<<dim3(32,32), 256, 0, stream>>>(w_in1, wt, DIMN, DIMN);
        gemm_bt<1><<<dim3(8,2), 256, 0, stream>>>(x_bf, wt, b_in1, nullptr, t1_bf,
                                                  nullptr, nullptr, LSEQ, DIMN, DIMN);
        transpose_cvt<<<dim3(64,32), 256, 0, stream>>>(w_in2, wt, DIMN, 2048);
        gemm_bt<2><<<dim3(16,2), 256, 0, stream>>>(t1_bf, wt, b_in2, nullptr, nullptr,
                                                   XC, Aseq, LSEQ, 2048, DIMN);
        uext_kernel<<<(LSEQ+1)*HD/256, 256, 0, stream>>>(Vinv, hidr, hidi, XC, Uext);
        scan_kernel<<<1, 512, 0, stream>>>(Uext, Aseq, S);
        vmul_kernel<<<LSEQ*HD/256, 256, 0, stream>>>(Vr, Vi, S, hr_bf, out + LSEQ*DIMN, tail_n);
        transpose_cvt<<<dim3(32,32), 256, 0, stream>>>(w_out1, wt, DIMN, DIMN);
        gemm_bt<1><<<dim3(8,2), 256, 0, stream>>>(hr_bf, wt, b_out1, nullptr, y1_bf,
                                                  nullptr, nullptr, LSEQ, DIMN, DIMN);
        transpose_cvt<<<dim3(32,32), 256, 0, stream>>>(w_out2, wt, DIMN, DIMN);
        gemm_bt<0><<<dim3(8,2), 256, 0, stream>>>(y1_bf, wt, b_out2, out, nullptr,
                                                  nullptr, nullptr, LSEQ, DIMN, DIMN);
    }
}

// Round 10
// 303.494 us; speedup vs baseline: 1.7298x; 1.1347x over previous
//
#include <hip/hip_runtime.h>
#include <math.h>

#define DIMN 1024
#define NH 8
#define ND 64
#define LSEQ 256
#define HD 512      // NH*ND

typedef __attribute__((ext_vector_type(8))) short short8;
typedef __attribute__((ext_vector_type(4))) float f32x4;

__device__ __forceinline__ float2 cmul(float2 a, float2 b){
    return make_float2(a.x*b.x - a.y*b.y, a.x*b.y + a.y*b.x);
}
__device__ __forceinline__ ushort f2bf(float f){
    union { float f; unsigned u; } v; v.f = f;
    unsigned r = v.u + 0x7FFF + ((v.u >> 16) & 1);   // RNE
    return (ushort)(r >> 16);
}

#define ISTR 65

// ---------- fused prep: blocks 0-7 = per-head inverse (in-place GJ);
// blocks 8-135 = x->bf16 cast; blocks 136+ = weight transposes (2 tiles/blk).
__global__ __launch_bounds__(512) void prep_kernel(
        const float* __restrict__ x,
        const float* __restrict__ w1, const float* __restrict__ w2,
        const float* __restrict__ w3, const float* __restrict__ w4,
        const float* __restrict__ Vr, const float* __restrict__ Vi,
        ushort* __restrict__ x_bf,
        ushort* __restrict__ w1t, ushort* __restrict__ w2t,
        ushort* __restrict__ w3t, ushort* __restrict__ w4t,
        float2* __restrict__ Vinv){
    __shared__ float2 Mx[64*ISTR];
    const int b = blockIdx.x;
    const int tid = threadIdx.x;

    if (b < 8){
        const int h = b;
        for (int idx = tid; idx < 4096; idx += 512){
            int i = idx >> 6, j = idx & 63;
            Mx[i*ISTR + j] = make_float2(Vr[h*4096 + idx], Vi[h*4096 + idx]);
        }
        __syncthreads();
        const int w = tid >> 6, l = tid & 63;
        const int rbase = w*8;
        for (int k = 0; k < 64; ++k){
            float2 d = Mx[k*ISTR + k];
            float im = 1.f/(d.x*d.x + d.y*d.y);
            float2 p = make_float2(d.x*im, -d.y*im);
            float2 prl = Mx[k*ISTR + l];
            float2 spr = (l == k) ? p : cmul(prl, p);
            float2 fv[8];
            #pragma unroll
            for (int rr = 0; rr < 8; ++rr)
                fv[rr] = Mx[(rbase+rr)*ISTR + k];
            __syncthreads();
            #pragma unroll
            for (int rr = 0; rr < 8; ++rr){
                int r = rbase + rr;
                if (r == k){
                    Mx[r*ISTR + l] = spr;
                } else {
                    float2 f  = fv[rr];
                    float2 v0 = Mx[r*ISTR + l];
                    if (l == k){ v0.x = 0.f; v0.y = 0.f; }
                    v0.x -= f.x*spr.x - f.y*spr.y;
                    v0.y -= f.x*spr.y + f.y*spr.x;
                    Mx[r*ISTR + l] = v0;
                }
            }
            __syncthreads();
        }
        for (int idx = tid; idx < 4096; idx += 512){
            int i = idx >> 6, j = idx & 63;
            Vinv[h*4096 + idx] = Mx[i*ISTR + j];
        }
        return;
    }

    int widx = b - 8;
    if (widx < 128){
        int i = widx*512 + tid;
        float4 v = ((const float4*)x)[i];
        ushort4 u; u.x=f2bf(v.x); u.y=f2bf(v.y); u.z=f2bf(v.z); u.w=f2bf(v.w);
        ((ushort4*)x_bf)[i] = u;
        return;
    }
    widx -= 128;

    const float* W; ushort* Wt; int K = 1024, N;
    if (widx < 512)            { W = w1; Wt = w1t; N = 1024; }
    else if (widx < 1536)      { W = w2; Wt = w2t; N = 2048; widx -= 512; }
    else if (widx < 2048)      { W = w3; Wt = w3t; N = 1024; widx -= 1536; }
    else                       { W = w4; Wt = w4t; N = 1024; widx -= 2048; }
    const int half = tid >> 8;
    const int t = widx*2 + half;
    const int tiles_n = N >> 5;
    const int n0 = (t % tiles_n) * 32, k0 = (t / tiles_n) * 32;
    float* tile = (float*)Mx + half*(32*33);
    const int tx = tid & 31, ty = (tid >> 5) & 7;
    #pragma unroll
    for (int i = 0; i < 4; ++i)
        tile[(ty + i*8)*33 + tx] = W[(k0 + ty + i*8)*N + n0 + tx];
    __syncthreads();
    #pragma unroll
    for (int i = 0; i < 4; ++i){
        int r = ty + i*8;
        Wt[(n0 + r)*K + k0 + tx] = f2bf(tile[tx*33 + r]);
    }
}

// ---------- serial-fallback kernels (used only if ws too small) ----------
__global__ __launch_bounds__(512) void inv_kernel(const float* __restrict__ Vr,
                                                  const float* __restrict__ Vi,
                                                  float2* __restrict__ Vinv){
    __shared__ float2 Mx[64*ISTR];
    const int h = blockIdx.x;
    const int tid = threadIdx.x;
    for (int idx = tid; idx < 4096; idx += 512){
        int i = idx >> 6, j = idx & 63;
        Mx[i*ISTR + j] = make_float2(Vr[h*4096 + idx], Vi[h*4096 + idx]);
    }
    __syncthreads();
    const int w = tid >> 6, l = tid & 63;
    const int rbase = w*8;
    for (int k = 0; k < 64; ++k){
        float2 d = Mx[k*ISTR + k];
        float im = 1.f/(d.x*d.x + d.y*d.y);
        float2 p = make_float2(d.x*im, -d.y*im);
        float2 prl = Mx[k*ISTR + l];
        float2 spr = (l == k) ? p : cmul(prl, p);
        float2 fv[8];
        #pragma unroll
        for (int rr = 0; rr < 8; ++rr)
            fv[rr] = Mx[(rbase+rr)*ISTR + k];
        __syncthreads();
        #pragma unroll
        for (int rr = 0; rr < 8; ++rr){
            int r = rbase + rr;
            if (r == k){
                Mx[r*ISTR + l] = spr;
            } else {
                float2 f  = fv[rr];
                float2 v0 = Mx[r*ISTR + l];
                if (l == k){ v0.x = 0.f; v0.y = 0.f; }
                v0.x -= f.x*spr.x - f.y*spr.y;
                v0.y -= f.x*spr.y + f.y*spr.x;
                Mx[r*ISTR + l] = v0;
            }
        }
        __syncthreads();
    }
    for (int idx = tid; idx < 4096; idx += 512){
        int i = idx >> 6, j = idx & 63;
        Vinv[h*4096 + idx] = Mx[i*ISTR + j];
    }
}

__global__ __launch_bounds__(256) void transpose_cvt(const float* __restrict__ W,
                 ushort* __restrict__ Wt, int K, int N){
    __shared__ float tile[32][33];
    const int n0 = blockIdx.x * 32, k0 = blockIdx.y * 32;
    const int tx = threadIdx.x & 31, ty = threadIdx.x >> 5;
    #pragma unroll
    for (int i = 0; i < 4; ++i)
        tile[ty + i*8][tx] = W[(k0 + ty + i*8)*N + n0 + tx];
    __syncthreads();
    #pragma unroll
    for (int i = 0; i < 4; ++i){
        int r = ty + i*8;
        Wt[(n0 + r)*K + k0 + tx] = f2bf(tile[tx][r]);
    }
}

__global__ __launch_bounds__(256) void cvt_bf16_kernel(const float* __restrict__ in,
                                 ushort* __restrict__ o, int n4){
    int i = blockIdx.x*256 + threadIdx.x;
    if (i < n4){
        float4 v = ((const float4*)in)[i];
        ushort4 u; u.x=f2bf(v.x); u.y=f2bf(v.y); u.z=f2bf(v.z); u.w=f2bf(v.w);
        ((ushort4*)o)[i] = u;
    }
}

// ---------- bf16 MFMA GEMM: C(MxN) = act(A(MxK) @ Bt(NxK)^T + bias) ----------
#define BM 128
#define BN 128
#define BK 32
#define ASTR 40
template<int ACT>
__global__ __launch_bounds__(256) void gemm_bt(const ushort* __restrict__ A,
                 const ushort* __restrict__ Bt, const float* __restrict__ bias,
                 float* __restrict__ Cf, ushort* __restrict__ Cb,
                 float2* __restrict__ XCo, float2* __restrict__ Ao,
                 int M, int N, int K){
    __shared__ ushort As[BM*ASTR];
    __shared__ ushort Bs[BN*ASTR];
    const int tid = threadIdx.x;
    const int bm = blockIdx.y * BM, bn = blockIdx.x * BN;
    const int wave = tid >> 6, l = tid & 63;
    const int wr = (wave >> 1) * 64, wc = (wave & 1) * 64;
    const int ml = l & 15, quad = l >> 4;
    f32x4 acc[4][4];
    #pragma unroll
    for (int i=0;i<4;++i)
        #pragma unroll
        for (int j=0;j<4;++j) acc[i][j] = (f32x4){0.f,0.f,0.f,0.f};

    const int c0r = tid >> 1;
    const int c0s = (tid & 1) * 2;
    for (int k0 = 0; k0 < K; k0 += BK){
        uint4 av0 = *(const uint4*)&A [(bm + c0r)*K + k0 + c0s*8];
        uint4 av1 = *(const uint4*)&A [(bm + c0r)*K + k0 + c0s*8 + 8];
        uint4 bv0 = *(const uint4*)&Bt[(bn + c0r)*K + k0 + c0s*8];
        uint4 bv1 = *(const uint4*)&Bt[(bn + c0r)*K + k0 + c0s*8 + 8];
        __syncthreads();
        *(uint4*)&As[c0r*ASTR + c0s*8]     = av0;
        *(uint4*)&As[c0r*ASTR + c0s*8 + 8] = av1;
        *(uint4*)&Bs[c0r*ASTR + c0s*8]     = bv0;
        *(uint4*)&Bs[c0r*ASTR + c0s*8 + 8] = bv1;
        __syncthreads();
        short8 af[4], bfv[4];
        #pragma unroll
        for (int f=0; f<4; ++f){
            af[f]  = *(const short8*)&As[(wr + f*16 + ml)*ASTR + quad*8];
            bfv[f] = *(const short8*)&Bs[(wc + f*16 + ml)*ASTR + quad*8];
        }
        #pragma unroll
        for (int i=0;i<4;++i)
            #pragma unroll
            for (int j=0;j<4;++j)
                acc[i][j] = __builtin_amdgcn_mfma_f32_16x16x32_bf16(af[i], bfv[j], acc[i][j], 0,0,0);
    }
    #pragma unroll
    for (int i=0;i<4;++i){
        #pragma unroll
        for (int j=0;j<4;++j){
            const int gcol = bn + wc + j*16 + ml;
            const float bsv = bias[gcol];
            #pragma unroll
            for (int r=0;r<4;++r){
                const int grow = bm + wr + i*16 + quad*4 + r;
                float val = acc[i][j][r] + bsv;
                if (ACT == 2){
                    float v1 = __shfl_down(val, 1);
                    float v2 = __shfl_down(val, 2);
                    float v3 = __shfl_down(val, 3);
                    if ((l & 3) == 0){
                        int hd = gcol >> 2;
                        XCo[grow*HD + hd] = make_float2(val, v1);
                        float m2 = v2*v2 + v3*v3;
                        float s = sqrtf(m2)/(1.f + m2);
                        Ao[grow*HD + hd] = make_float2(v2*s, v3*s);
                    }
                } else if (ACT == 1){
                    val *= 1.f/(1.f + expf(-val));
                    Cb[grow*N + gcol] = f2bf(val);
                } else {
                    Cf[grow*N + gcol] = val;
                }
            }
        }
    }
}

// ---------- u[c] = Vinv_h @ (c==0 ? hidden : xc[c-1]),  c = 0..256 ----------
__global__ __launch_bounds__(256) void uext_kernel(const float2* __restrict__ Vinv,
                            const float* __restrict__ hre, const float* __restrict__ him,
                            const float2* __restrict__ XC, float2* __restrict__ Uext){
    int g = blockIdx.x*256 + threadIdx.x;
    int c = g >> 9;
    int hn = g & 511;
    int h = hn >> 6;
    const float2* vrow = &Vinv[hn*64];
    float2 acc = make_float2(0.f, 0.f);
    if (c == 0){
        #pragma unroll 8
        for (int o=0;o<64;++o){
            float2 x = make_float2(hre[h*64+o], him[h*64+o]);
            float2 p = cmul(vrow[o], x);
            acc.x += p.x; acc.y += p.y;
        }
    } else {
        const float2* xrow = &XC[(c-1)*HD + h*64];
        #pragma unroll 8
        for (int o=0;o<64;++o){
            float2 p = cmul(vrow[o], xrow[o]);
            acc.x += p.x; acc.y += p.y;
        }
    }
    Uext[g] = acc;
}

// ---------- PARALLEL scan (Hillis-Steele over m, one block per channel) ----------
// Affine maps T=(A,U): st[m] = T.A*init + T.U, combine(cur∘prev) =
// (cur.A*prev.A, cur.A*prev.U + cur.U). 8 rounds, double-buffered LDS.
__global__ __launch_bounds__(LSEQ) void pscan_kernel(const float2* __restrict__ Uext,
                            const float2* __restrict__ Aseq, float2* __restrict__ S){
    __shared__ float4 buf[2][LSEQ];
    const int hn = blockIdx.x;
    const int m = threadIdx.x;
    float2 a = Aseq[m*HD + hn];
    float2 u = Uext[(m+1)*HD + hn];
    buf[0][m] = make_float4(a.x, a.y, u.x, u.y);
    __syncthreads();
    int pb = 0;
    #pragma unroll
    for (int d = 1; d < LSEQ; d <<= 1){
        float4 cur = buf[pb][m];
        float4 out = cur;
        if (m >= d){
            float4 prev = buf[pb][m-d];
            float2 cA = make_float2(cur.x, cur.y), cU = make_float2(cur.z, cur.w);
            float2 pA = make_float2(prev.x, prev.y), pU = make_float2(prev.z, prev.w);
            float2 nA = cmul(cA, pA);
            float2 nU = cmul(cA, pU);
            nU.x += cU.x; nU.y += cU.y;
            out = make_float4(nA.x, nA.y, nU.x, nU.y);
        }
        buf[pb^1][m] = out;
        pb ^= 1;
        __syncthreads();
    }
    float4 t = buf[pb][m];
    float2 init = Uext[hn];
    float2 st = cmul(make_float2(t.x, t.y), init);
    st.x += t.z; st.y += t.w;
    S[m*HD + hn] = st;
}

// ---------- h[m] = V_h @ S[m]; hr as bf16; fp32 tail ----------
__global__ __launch_bounds__(256) void vmul_kernel(const float* __restrict__ Vr,
                            const float* __restrict__ Vi,
                            const float2* __restrict__ S, ushort* __restrict__ hrb,
                            float* __restrict__ out_tail, int tail_n){
    int g = blockIdx.x*256 + threadIdx.x;
    int m = g >> 9, hn = g & 511;
    int h = hn >> 6;
    const float* vr = &Vr[hn*64];
    const float* vi = &Vi[hn*64];
    const float2* srow = &S[m*HD + h*64];
    float2 acc = make_float2(0.f, 0.f);
    #pragma unroll 8
    for (int o=0;o<64;++o){
        float2 v = make_float2(vr[o], vi[o]);
        float2 p = cmul(v, srow[o]);
        acc.x += p.x; acc.y += p.y;
    }
    hrb[m*DIMN + hn*2]   = f2bf(acc.x);
    hrb[m*DIMN + hn*2+1] = f2bf(acc.y);
    if (m == LSEQ-1){
        if (tail_n >= 1024){
            out_tail[hn]       = acc.x;
            out_tail[512 + hn] = acc.y;
        } else if (tail_n >= 512){
            out_tail[hn] = acc.x;
        }
    }
}

extern "C" void kernel_launch(void* const* d_in, const int* in_sizes, int n_in,
                              void* d_out, int out_size, void* d_ws, size_t ws_size,
                              hipStream_t stream) {
    const float* x      = (const float*)d_in[0];
    const float* hidr   = (const float*)d_in[1];
    const float* hidi   = (const float*)d_in[2];
    const float* w_in1  = (const float*)d_in[3];
    const float* b_in1  = (const float*)d_in[4];
    const float* w_in2  = (const float*)d_in[5];
    const float* b_in2  = (const float*)d_in[6];
    const float* w_out1 = (const float*)d_in[7];
    const float* b_out1 = (const float*)d_in[8];
    const float* w_out2 = (const float*)d_in[9];
    const float* b_out2 = (const float*)d_in[10];
    const float* Vr     = (const float*)d_in[11];
    const float* Vi     = (const float*)d_in[12];
    float* out = (float*)d_out;
    const int tail_n = out_size - LSEQ*DIMN;
    char* ws = (char*)d_ws;

    if (ws_size >= 14946304u){
        float2* Vinv  = (float2*)(ws + 0);          // 262144
        ushort* w1t   = (ushort*)(ws + 262144);     // 2 MB
        ushort* w2t   = (ushort*)(ws + 2359296);    // 4 MB
        ushort* w3t   = (ushort*)(ws + 6553600);    // 2 MB
        ushort* w4t   = (ushort*)(ws + 8650752);    // 2 MB
        ushort* x_bf  = (ushort*)(ws + 10747904);   // 512 KB (reused as y1_bf)
        ushort* t1_bf = (ushort*)(ws + 11272192);   // 512 KB (reused as hr_bf)
        float2* XC    = (float2*)(ws + 11796480);   // 1 MB (reused as S)
        float2* Aseq  = (float2*)(ws + 12845056);   // 1 MB
        float2* Uext  = (float2*)(ws + 13893632);   // 1052672
        ushort* y1_bf = x_bf;
        ushort* hr_bf = t1_bf;
        float2* S     = XC;

        prep_kernel<<<2696, 512, 0, stream>>>(x, w_in1, w_in2, w_out1, w_out2,
                                              Vr, Vi, x_bf, w1t, w2t, w3t, w4t, Vinv);
        gemm_bt<1><<<dim3(8,2), 256, 0, stream>>>(x_bf, w1t, b_in1, nullptr, t1_bf,
                                                  nullptr, nullptr, LSEQ, DIMN, DIMN);
        gemm_bt<2><<<dim3(16,2), 256, 0, stream>>>(t1_bf, w2t, b_in2, nullptr, nullptr,
                                                   XC, Aseq, LSEQ, 2048, DIMN);
        uext_kernel<<<(LSEQ+1)*HD/256, 256, 0, stream>>>(Vinv, hidr, hidi, XC, Uext);
        pscan_kernel<<<HD, LSEQ, 0, stream>>>(Uext, Aseq, S);
        vmul_kernel<<<LSEQ*HD/256, 256, 0, stream>>>(Vr, Vi, S, hr_bf, out + LSEQ*DIMN, tail_n);
        gemm_bt<1><<<dim3(8,2), 256, 0, stream>>>(hr_bf, w3t, b_out1, nullptr, y1_bf,
                                                  nullptr, nullptr, LSEQ, DIMN, DIMN);
        gemm_bt<0><<<dim3(8,2), 256, 0, stream>>>(y1_bf, w4t, b_out2, out, nullptr,
                                                  nullptr, nullptr, LSEQ, DIMN, DIMN);
    } else {
        float2* Vinv  = (float2*)(ws + 0);
        ushort* wt    = (ushort*)(ws + 262144);
        ushort* x_bf  = (ushort*)(ws + 4456448);
        ushort* t1_bf = (ushort*)(ws + 4980736);
        float2* XC    = (float2*)(ws + 5505024);
        float2* Aseq  = (float2*)(ws + 6553600);
        float2* Uext  = (float2*)(ws + 7602176);
        ushort* y1_bf = x_bf;
        ushort* hr_bf = t1_bf;
        float2* S     = XC;

        inv_kernel<<<NH, 512, 0, stream>>>(Vr, Vi, Vinv);
        cvt_bf16_kernel<<<LSEQ*DIMN/4/256, 256, 0, stream>>>(x, x_bf, LSEQ*DIMN/4);
        transpose_cvt<<<dim3(32,32), 256, 0, stream>>>(w_in1, wt, DIMN, DIMN);
        gemm_bt<1><<<dim3(8,2), 256, 0, stream>>>(x_bf, wt, b_in1, nullptr, t1_bf,
                                                  nullptr, nullptr, LSEQ, DIMN, DIMN);
        transpose_cvt<<<dim3(64,32), 256, 0, stream>>>(w_in2, wt, DIMN, 2048);
        gemm_bt<2><<<dim3(16,2), 256, 0, stream>>>(t1_bf, wt, b_in2, nullptr, nullptr,
                                                   XC, Aseq, LSEQ, 2048, DIMN);
        uext_kernel<<<(LSEQ+1)*HD/256, 256, 0, stream>>>(Vinv, hidr, hidi, XC, Uext);
        pscan_kernel<<<HD, LSEQ, 0, stream>>>(Uext, Aseq, S);
        vmul_kernel<<<LSEQ*HD/256, 256, 0, stream>>>(Vr, Vi, S, hr_bf, out + LSEQ*DIMN, tail_n);
        transpose_cvt<<<dim3(32,32), 256, 0, stream>>>(w_out1, wt, DIMN, DIMN);
        gemm_bt<1><<<dim3(8,2), 256, 0, stream>>>(hr_bf, wt, b_out1, nullptr, y1_bf,
                                                  nullptr, nullptr, LSEQ, DIMN, DIMN);
        transpose_cvt<<<dim3(32,32), 256, 0, stream>>>(w_out2, wt, DIMN, DIMN);
        gemm_bt<0><<<dim3(8,2), 256, 0, stream>>>(y1_bf, wt, b_out2, out, nullptr,
                                                  nullptr, nullptr, LSEQ, DIMN, DIMN);
    }
}

// Round 11
// 280.216 us; speedup vs baseline: 1.8735x; 1.0831x over previous
//
#include <hip/hip_runtime.h>
#include <math.h>

#define DIMN 1024
#define NH 8
#define ND 64
#define LSEQ 256
#define HD 512      // NH*ND

typedef __attribute__((ext_vector_type(8))) short short8;
typedef __attribute__((ext_vector_type(4))) float f32x4;

__device__ __forceinline__ float2 cmul(float2 a, float2 b){
    return make_float2(a.x*b.x - a.y*b.y, a.x*b.y + a.y*b.x);
}
__device__ __forceinline__ ushort f2bf(float f){
    union { float f; unsigned u; } v; v.f = f;
    unsigned r = v.u + 0x7FFF + ((v.u >> 16) & 1);   // RNE
    return (ushort)(r >> 16);
}

#define ISTR 65

// ---------- blocked (NB=8) in-place Gauss-Jordan, 512 threads ----------
// Macro-step: wave 0 factorizes 64x8 panel in REGISTERS (8 unrolled GJ steps,
// shfl broadcast, static indices only); rank-8 update by all waves:
// M[i][j] = [i-not-in-blk]*M[i][j] + sum_m P[i][m]*Mold[k0+m][j]  (j not in blk).
// P = finalized block columns (broadcast reads, never written in update).
// Block-row values pre-read to regs before the write barrier. 3 barriers/macro.
__device__ __forceinline__ void inv_gj_blocked(const float* __restrict__ Vr,
        const float* __restrict__ Vi, float2* __restrict__ Vinv,
        int h, int tid, float2* Mx){
    for (int idx = tid; idx < 4096; idx += 512){
        int i = idx >> 6, j = idx & 63;
        Mx[i*ISTR + j] = make_float2(Vr[h*4096 + idx], Vi[h*4096 + idx]);
    }
    __syncthreads();
    const int w = tid >> 6, l = tid & 63;
    const int rbase = w*8;
    for (int kb = 0; kb < 8; ++kb){
        const int k0 = kb*8;
        if (w == 0){
            // ---- panel factorization: lane l = row l, pr[m] = panel cols ----
            float2 pr[8];
            #pragma unroll
            for (int m = 0; m < 8; ++m) pr[m] = Mx[l*ISTR + k0 + m];
            #pragma unroll
            for (int k = 0; k < 8; ++k){
                const int gk = k0 + k;
                float2 d; d.x = __shfl(pr[k].x, gk); d.y = __shfl(pr[k].y, gk);
                float im = 1.f/(d.x*d.x + d.y*d.y);
                float2 p = make_float2(d.x*im, -d.y*im);
                float2 spr[8];
                #pragma unroll
                for (int m = 0; m < 8; ++m){
                    float2 t; t.x = __shfl(pr[m].x, gk); t.y = __shfl(pr[m].y, gk);
                    spr[m] = (m == k) ? p : cmul(t, p);
                }
                float2 f = pr[k];
                if (l == gk){
                    #pragma unroll
                    for (int m = 0; m < 8; ++m) pr[m] = spr[m];
                } else {
                    #pragma unroll
                    for (int m = 0; m < 8; ++m){
                        float2 u = cmul(f, spr[m]);
                        if (m == k){ pr[m].x = -u.x;  pr[m].y = -u.y;  }
                        else       { pr[m].x -= u.x;  pr[m].y -= u.y;  }
                    }
                }
            }
            #pragma unroll
            for (int m = 0; m < 8; ++m) Mx[l*ISTR + k0 + m] = pr[m];
        }
        __syncthreads();            // B1: panel visible
        float2 br[8];               // block rows, my column
        #pragma unroll
        for (int m = 0; m < 8; ++m) br[m] = Mx[(k0+m)*ISTR + l];
        __syncthreads();            // B2: cross-reads done before writes
        if (((unsigned)(l - k0)) >= 8u){     // block columns are final; skip
            #pragma unroll
            for (int rr = 0; rr < 8; ++rr){
                const int r = rbase + rr;
                float2 acc;
                if (((unsigned)(r - k0)) < 8u){ acc.x = 0.f; acc.y = 0.f; }
                else acc = Mx[r*ISTR + l];
                #pragma unroll
                for (int m = 0; m < 8; ++m){
                    float2 Pv = Mx[r*ISTR + k0 + m];   // wave-uniform broadcast
                    acc.x += Pv.x*br[m].x - Pv.y*br[m].y;
                    acc.y += Pv.x*br[m].y + Pv.y*br[m].x;
                }
                Mx[r*ISTR + l] = acc;
            }
        }
        __syncthreads();            // B3: writes done before next panel
    }
    for (int idx = tid; idx < 4096; idx += 512){
        int i = idx >> 6, j = idx & 63;
        Vinv[h*4096 + idx] = Mx[i*ISTR + j];
    }
}

// ---------- fused prep: blocks 0-7 = per-head inverse (blocked GJ);
// blocks 8-135 = x->bf16 cast; blocks 136+ = weight transposes (2 tiles/blk).
__global__ __launch_bounds__(512) void prep_kernel(
        const float* __restrict__ x,
        const float* __restrict__ w1, const float* __restrict__ w2,
        const float* __restrict__ w3, const float* __restrict__ w4,
        const float* __restrict__ Vr, const float* __restrict__ Vi,
        ushort* __restrict__ x_bf,
        ushort* __restrict__ w1t, ushort* __restrict__ w2t,
        ushort* __restrict__ w3t, ushort* __restrict__ w4t,
        float2* __restrict__ Vinv){
    __shared__ float2 Mx[64*ISTR];
    const int b = blockIdx.x;
    const int tid = threadIdx.x;

    if (b < 8){
        inv_gj_blocked(Vr, Vi, Vinv, b, tid, Mx);
        return;
    }

    int widx = b - 8;
    if (widx < 128){
        int i = widx*512 + tid;
        float4 v = ((const float4*)x)[i];
        ushort4 u; u.x=f2bf(v.x); u.y=f2bf(v.y); u.z=f2bf(v.z); u.w=f2bf(v.w);
        ((ushort4*)x_bf)[i] = u;
        return;
    }
    widx -= 128;

    const float* W; ushort* Wt; int K = 1024, N;
    if (widx < 512)            { W = w1; Wt = w1t; N = 1024; }
    else if (widx < 1536)      { W = w2; Wt = w2t; N = 2048; widx -= 512; }
    else if (widx < 2048)      { W = w3; Wt = w3t; N = 1024; widx -= 1536; }
    else                       { W = w4; Wt = w4t; N = 1024; widx -= 2048; }
    const int half = tid >> 8;
    const int t = widx*2 + half;
    const int tiles_n = N >> 5;
    const int n0 = (t % tiles_n) * 32, k0 = (t / tiles_n) * 32;
    float* tile = (float*)Mx + half*(32*33);
    const int tx = tid & 31, ty = (tid >> 5) & 7;
    #pragma unroll
    for (int i = 0; i < 4; ++i)
        tile[(ty + i*8)*33 + tx] = W[(k0 + ty + i*8)*N + n0 + tx];
    __syncthreads();
    #pragma unroll
    for (int i = 0; i < 4; ++i){
        int r = ty + i*8;
        Wt[(n0 + r)*K + k0 + tx] = f2bf(tile[tx*33 + r]);
    }
}

// ---------- serial-fallback kernels (used only if ws too small) ----------
__global__ __launch_bounds__(512) void inv_kernel(const float* __restrict__ Vr,
                                                  const float* __restrict__ Vi,
                                                  float2* __restrict__ Vinv){
    __shared__ float2 Mx[64*ISTR];
    const int h = blockIdx.x;
    const int tid = threadIdx.x;
    for (int idx = tid; idx < 4096; idx += 512){
        int i = idx >> 6, j = idx & 63;
        Mx[i*ISTR + j] = make_float2(Vr[h*4096 + idx], Vi[h*4096 + idx]);
    }
    __syncthreads();
    const int w = tid >> 6, l = tid & 63;
    const int rbase = w*8;
    for (int k = 0; k < 64; ++k){
        float2 d = Mx[k*ISTR + k];
        float im = 1.f/(d.x*d.x + d.y*d.y);
        float2 p = make_float2(d.x*im, -d.y*im);
        float2 prl = Mx[k*ISTR + l];
        float2 spr = (l == k) ? p : cmul(prl, p);
        float2 fv[8];
        #pragma unroll
        for (int rr = 0; rr < 8; ++rr)
            fv[rr] = Mx[(rbase+rr)*ISTR + k];
        __syncthreads();
        #pragma unroll
        for (int rr = 0; rr < 8; ++rr){
            int r = rbase + rr;
            if (r == k){
                Mx[r*ISTR + l] = spr;
            } else {
                float2 f  = fv[rr];
                float2 v0 = Mx[r*ISTR + l];
                if (l == k){ v0.x = 0.f; v0.y = 0.f; }
                v0.x -= f.x*spr.x - f.y*spr.y;
                v0.y -= f.x*spr.y + f.y*spr.x;
                Mx[r*ISTR + l] = v0;
            }
        }
        __syncthreads();
    }
    for (int idx = tid; idx < 4096; idx += 512){
        int i = idx >> 6, j = idx & 63;
        Vinv[h*4096 + idx] = Mx[i*ISTR + j];
    }
}

__global__ __launch_bounds__(256) void transpose_cvt(const float* __restrict__ W,
                 ushort* __restrict__ Wt, int K, int N){
    __shared__ float tile[32][33];
    const int n0 = blockIdx.x * 32, k0 = blockIdx.y * 32;
    const int tx = threadIdx.x & 31, ty = threadIdx.x >> 5;
    #pragma unroll
    for (int i = 0; i < 4; ++i)
        tile[ty + i*8][tx] = W[(k0 + ty + i*8)*N + n0 + tx];
    __syncthreads();
    #pragma unroll
    for (int i = 0; i < 4; ++i){
        int r = ty + i*8;
        Wt[(n0 + r)*K + k0 + tx] = f2bf(tile[tx][r]);
    }
}

__global__ __launch_bounds__(256) void cvt_bf16_kernel(const float* __restrict__ in,
                                 ushort* __restrict__ o, int n4){
    int i = blockIdx.x*256 + threadIdx.x;
    if (i < n4){
        float4 v = ((const float4*)in)[i];
        ushort4 u; u.x=f2bf(v.x); u.y=f2bf(v.y); u.z=f2bf(v.z); u.w=f2bf(v.w);
        ((ushort4*)o)[i] = u;
    }
}

// ---------- bf16 MFMA GEMM: C(MxN) = act(A(MxK) @ Bt(NxK)^T + bias) ----------
#define BM 128
#define BN 128
#define BK 32
#define ASTR 40
template<int ACT>
__global__ __launch_bounds__(256) void gemm_bt(const ushort* __restrict__ A,
                 const ushort* __restrict__ Bt, const float* __restrict__ bias,
                 float* __restrict__ Cf, ushort* __restrict__ Cb,
                 float2* __restrict__ XCo, float2* __restrict__ Ao,
                 int M, int N, int K){
    __shared__ ushort As[BM*ASTR];
    __shared__ ushort Bs[BN*ASTR];
    const int tid = threadIdx.x;
    const int bm = blockIdx.y * BM, bn = blockIdx.x * BN;
    const int wave = tid >> 6, l = tid & 63;
    const int wr = (wave >> 1) * 64, wc = (wave & 1) * 64;
    const int ml = l & 15, quad = l >> 4;
    f32x4 acc[4][4];
    #pragma unroll
    for (int i=0;i<4;++i)
        #pragma unroll
        for (int j=0;j<4;++j) acc[i][j] = (f32x4){0.f,0.f,0.f,0.f};

    const int c0r = tid >> 1;
    const int c0s = (tid & 1) * 2;
    for (int k0 = 0; k0 < K; k0 += BK){
        uint4 av0 = *(const uint4*)&A [(bm + c0r)*K + k0 + c0s*8];
        uint4 av1 = *(const uint4*)&A [(bm + c0r)*K + k0 + c0s*8 + 8];
        uint4 bv0 = *(const uint4*)&Bt[(bn + c0r)*K + k0 + c0s*8];
        uint4 bv1 = *(const uint4*)&Bt[(bn + c0r)*K + k0 + c0s*8 + 8];
        __syncthreads();
        *(uint4*)&As[c0r*ASTR + c0s*8]     = av0;
        *(uint4*)&As[c0r*ASTR + c0s*8 + 8] = av1;
        *(uint4*)&Bs[c0r*ASTR + c0s*8]     = bv0;
        *(uint4*)&Bs[c0r*ASTR + c0s*8 + 8] = bv1;
        __syncthreads();
        short8 af[4], bfv[4];
        #pragma unroll
        for (int f=0; f<4; ++f){
            af[f]  = *(const short8*)&As[(wr + f*16 + ml)*ASTR + quad*8];
            bfv[f] = *(const short8*)&Bs[(wc + f*16 + ml)*ASTR + quad*8];
        }
        #pragma unroll
        for (int i=0;i<4;++i)
            #pragma unroll
            for (int j=0;j<4;++j)
                acc[i][j] = __builtin_amdgcn_mfma_f32_16x16x32_bf16(af[i], bfv[j], acc[i][j], 0,0,0);
    }
    #pragma unroll
    for (int i=0;i<4;++i){
        #pragma unroll
        for (int j=0;j<4;++j){
            const int gcol = bn + wc + j*16 + ml;
            const float bsv = bias[gcol];
            #pragma unroll
            for (int r=0;r<4;++r){
                const int grow = bm + wr + i*16 + quad*4 + r;
                float val = acc[i][j][r] + bsv;
                if (ACT == 2){
                    float v1 = __shfl_down(val, 1);
                    float v2 = __shfl_down(val, 2);
                    float v3 = __shfl_down(val, 3);
                    if ((l & 3) == 0){
                        int hd = gcol >> 2;
                        XCo[grow*HD + hd] = make_float2(val, v1);
                        float m2 = v2*v2 + v3*v3;
                        float s = sqrtf(m2)/(1.f + m2);
                        Ao[grow*HD + hd] = make_float2(v2*s, v3*s);
                    }
                } else if (ACT == 1){
                    val *= 1.f/(1.f + expf(-val));
                    Cb[grow*N + gcol] = f2bf(val);
                } else {
                    Cf[grow*N + gcol] = val;
                }
            }
        }
    }
}

// ---------- u[c] = Vinv_h @ (c==0 ? hidden : xc[c-1]),  c = 0..256 ----------
__global__ __launch_bounds__(256) void uext_kernel(const float2* __restrict__ Vinv,
                            const float* __restrict__ hre, const float* __restrict__ him,
                            const float2* __restrict__ XC, float2* __restrict__ Uext){
    int g = blockIdx.x*256 + threadIdx.x;
    int c = g >> 9;
    int hn = g & 511;
    int h = hn >> 6;
    const float2* vrow = &Vinv[hn*64];
    float2 acc = make_float2(0.f, 0.f);
    if (c == 0){
        #pragma unroll 8
        for (int o=0;o<64;++o){
            float2 x = make_float2(hre[h*64+o], him[h*64+o]);
            float2 p = cmul(vrow[o], x);
            acc.x += p.x; acc.y += p.y;
        }
    } else {
        const float2* xrow = &XC[(c-1)*HD + h*64];
        #pragma unroll 8
        for (int o=0;o<64;++o){
            float2 p = cmul(vrow[o], xrow[o]);
            acc.x += p.x; acc.y += p.y;
        }
    }
    Uext[g] = acc;
}

// ---------- PARALLEL scan (Hillis-Steele over m, one block per channel) ----------
__global__ __launch_bounds__(LSEQ) void pscan_kernel(const float2* __restrict__ Uext,
                            const float2* __restrict__ Aseq, float2* __restrict__ S){
    __shared__ float4 buf[2][LSEQ];
    const int hn = blockIdx.x;
    const int m = threadIdx.x;
    float2 a = Aseq[m*HD + hn];
    float2 u = Uext[(m+1)*HD + hn];
    buf[0][m] = make_float4(a.x, a.y, u.x, u.y);
    __syncthreads();
    int pb = 0;
    #pragma unroll
    for (int d = 1; d < LSEQ; d <<= 1){
        float4 cur = buf[pb][m];
        float4 out = cur;
        if (m >= d){
            float4 prev = buf[pb][m-d];
            float2 cA = make_float2(cur.x, cur.y), cU = make_float2(cur.z, cur.w);
            float2 pA = make_float2(prev.x, prev.y), pU = make_float2(prev.z, prev.w);
            float2 nA = cmul(cA, pA);
            float2 nU = cmul(cA, pU);
            nU.x += cU.x; nU.y += cU.y;
            out = make_float4(nA.x, nA.y, nU.x, nU.y);
        }
        buf[pb^1][m] = out;
        pb ^= 1;
        __syncthreads();
    }
    float4 t = buf[pb][m];
    float2 init = Uext[hn];
    float2 st = cmul(make_float2(t.x, t.y), init);
    st.x += t.z; st.y += t.w;
    S[m*HD + hn] = st;
}

// ---------- h[m] = V_h @ S[m]; hr as bf16; fp32 tail ----------
__global__ __launch_bounds__(256) void vmul_kernel(const float* __restrict__ Vr,
                            const float* __restrict__ Vi,
                            const float2* __restrict__ S, ushort* __restrict__ hrb,
                            float* __restrict__ out_tail, int tail_n){
    int g = blockIdx.x*256 + threadIdx.x;
    int m = g >> 9, hn = g & 511;
    int h = hn >> 6;
    const float* vr = &Vr[hn*64];
    const float* vi = &Vi[hn*64];
    const float2* srow = &S[m*HD + h*64];
    float2 acc = make_float2(0.f, 0.f);
    #pragma unroll 8
    for (int o=0;o<64;++o){
        float2 v = make_float2(vr[o], vi[o]);
        float2 p = cmul(v, srow[o]);
        acc.x += p.x; acc.y += p.y;
    }
    hrb[m*DIMN + hn*2]   = f2bf(acc.x);
    hrb[m*DIMN + hn*2+1] = f2bf(acc.y);
    if (m == LSEQ-1){
        if (tail_n >= 1024){
            out_tail[hn]       = acc.x;
            out_tail[512 + hn] = acc.y;
        } else if (tail_n >= 512){
            out_tail[hn] = acc.x;
        }
    }
}

extern "C" void kernel_launch(void* const* d_in, const int* in_sizes, int n_in,
                              void* d_out, int out_size, void* d_ws, size_t ws_size,
                              hipStream_t stream) {
    const float* x      = (const float*)d_in[0];
    const float* hidr   = (const float*)d_in[1];
    const float* hidi   = (const float*)d_in[2];
    const float* w_in1  = (const float*)d_in[3];
    const float* b_in1  = (const float*)d_in[4];
    const float* w_in2  = (const float*)d_in[5];
    const float* b_in2  = (const float*)d_in[6];
    const float* w_out1 = (const float*)d_in[7];
    const float* b_out1 = (const float*)d_in[8];
    const float* w_out2 = (const float*)d_in[9];
    const float* b_out2 = (const float*)d_in[10];
    const float* Vr     = (const float*)d_in[11];
    const float* Vi     = (const float*)d_in[12];
    float* out = (float*)d_out;
    const int tail_n = out_size - LSEQ*DIMN;
    char* ws = (char*)d_ws;

    if (ws_size >= 14946304u){
        float2* Vinv  = (float2*)(ws + 0);          // 262144
        ushort* w1t   = (ushort*)(ws + 262144);     // 2 MB
        ushort* w2t   = (ushort*)(ws + 2359296);    // 4 MB
        ushort* w3t   = (ushort*)(ws + 6553600);    // 2 MB
        ushort* w4t   = (ushort*)(ws + 8650752);    // 2 MB
        ushort* x_bf  = (ushort*)(ws + 10747904);   // 512 KB (reused as y1_bf)
        ushort* t1_bf = (ushort*)(ws + 11272192);   // 512 KB (reused as hr_bf)
        float2* XC    = (float2*)(ws + 11796480);   // 1 MB (reused as S)
        float2* Aseq  = (float2*)(ws + 12845056);   // 1 MB
        float2* Uext  = (float2*)(ws + 13893632);   // 1052672
        ushort* y1_bf = x_bf;
        ushort* hr_bf = t1_bf;
        float2* S     = XC;

        prep_kernel<<<2696, 512, 0, stream>>>(x, w_in1, w_in2, w_out1, w_out2,
                                              Vr, Vi, x_bf, w1t, w2t, w3t, w4t, Vinv);
        gemm_bt<1><<<dim3(8,2), 256, 0, stream>>>(x_bf, w1t, b_in1, nullptr, t1_bf,
                                                  nullptr, nullptr, LSEQ, DIMN, DIMN);
        gemm_bt<2><<<dim3(16,2), 256, 0, stream>>>(t1_bf, w2t, b_in2, nullptr, nullptr,
                                                   XC, Aseq, LSEQ, 2048, DIMN);
        uext_kernel<<<(LSEQ+1)*HD/256, 256, 0, stream>>>(Vinv, hidr, hidi, XC, Uext);
        pscan_kernel<<<HD, LSEQ, 0, stream>>>(Uext, Aseq, S);
        vmul_kernel<<<LSEQ*HD/256, 256, 0, stream>>>(Vr, Vi, S, hr_bf, out + LSEQ*DIMN, tail_n);
        gemm_bt<1><<<dim3(8,2), 256, 0, stream>>>(hr_bf, w3t, b_out1, nullptr, y1_bf,
                                                  nullptr, nullptr, LSEQ, DIMN, DIMN);
        gemm_bt<0><<<dim3(8,2), 256, 0, stream>>>(y1_bf, w4t, b_out2, out, nullptr,
                                                  nullptr, nullptr, LSEQ, DIMN, DIMN);
    } else {
        float2* Vinv  = (float2*)(ws + 0);
        ushort* wt    = (ushort*)(ws + 262144);
        ushort* x_bf  = (ushort*)(ws + 4456448);
        ushort* t1_bf = (ushort*)(ws + 4980736);
        float2* XC    = (float2*)(ws + 5505024);
        float2* Aseq  = (float2*)(ws + 6553600);
        float2* Uext  = (float2*)(ws + 7602176);
        ushort* y1_bf = x_bf;
        ushort* hr_bf = t1_bf;
        float2* S     = XC;

        inv_kernel<<<NH, 512, 0, stream>>>(Vr, Vi, Vinv);
        cvt_bf16_kernel<<<LSEQ*DIMN/4/256, 256, 0, stream>>>(x, x_bf, LSEQ*DIMN/4);
        transpose_cvt<<<dim3(32,32), 256, 0, stream>>>(w_in1, wt, DIMN, DIMN);
        gemm_bt<1><<<dim3(8,2), 256, 0, stream>>>(x_bf, wt, b_in1, nullptr, t1_bf,
                                                  nullptr, nullptr, LSEQ, DIMN, DIMN);
        transpose_cvt<<<dim3(64,32), 256, 0, stream>>>(w_in2, wt, DIMN, 2048);
        gemm_bt<2><<<dim3(16,2), 256, 0, stream>>>(t1_bf, wt, b_in2, nullptr, nullptr,
                                                   XC, Aseq, LSEQ, 2048, DIMN);
        uext_kernel<<<(LSEQ+1)*HD/256, 256, 0, stream>>>(Vinv, hidr, hidi, XC, Uext);
        pscan_kernel<<<HD, LSEQ, 0, stream>>>(Uext, Aseq, S);
        vmul_kernel<<<LSEQ*HD/256, 256, 0, stream>>>(Vr, Vi, S, hr_bf, out + LSEQ*DIMN, tail_n);
        transpose_cvt<<<dim3(32,32), 256, 0, stream>>>(w_out1, wt, DIMN, DIMN);
        gemm_bt<1><<<dim3(8,2), 256, 0, stream>>>(hr_bf, wt, b_out1, nullptr, y1_bf,
                                                  nullptr, nullptr, LSEQ, DIMN, DIMN);
        transpose_cvt<<<dim3(32,32), 256, 0, stream>>>(w_out2, wt, DIMN, DIMN);
        gemm_bt<0><<<dim3(8,2), 256, 0, stream>>>(y1_bf, wt, b_out2, out, nullptr,
                                                  nullptr, nullptr, LSEQ, DIMN, DIMN);
    }
}